// Round 2
// baseline (554.944 us; speedup 1.0000x reference)
//
#include <hip/hip_runtime.h>
#include <hip/hip_fp16.h>

// ---------------------------------------------------------------------------
// GCN: 2x GraphConv (norm='both') + FC.  fp32 math, fp16 intermediates.
// R2..R8: 5943 -> 325 us (CSR gather, fold FC, MFMA GEMMs, fp16, no atomics).
// R9: reservation partition (323 us).
// R10: gather+gemm fusion REGRESSED (394 us): occupancy 68%->16%. Reverted.
// R11: gather1 16 lanes x half8; CHUNK 4096.
// R12: column-sliced gather128, slice = blockIdx&7. REGRESSED (351 us):
//      FETCH only 178->153 MB -> blockIdx%8 does NOT map to XCD on this
//      dispatch; affinity broken + 32B granules + 8x csr re-read.
// R13: REAL affinity: read HW_REG_XCC_ID in-kernel (learn_hip m09), persistent
//      2048-block grid, per-slice atomic work counters. Blocks on XCD s drain
//      slice s (3.2 MB, L2-resident), then steal other slices (correctness
//      independent of mapping). Expect gather FETCH ~90 MB, dur ~30 us.
// ---------------------------------------------------------------------------

#define CHUNK    4096   // edges per partition block
#define NB       256    // coarse buckets (node>>9; ceil(100000/512)=196)
#define SLAB     9216   // per-bucket slab capacity (mean 8163 + ~11 sigma)

typedef __attribute__((ext_vector_type(8))) short bf16x8;
typedef __attribute__((ext_vector_type(4))) float f32x4;

struct __align__(8)  half4 { __half x, y, z, w; };
struct __align__(16) half8 { __half h[8]; };

__device__ __forceinline__ unsigned short f2bf(float f) {
    union { float f; unsigned u; } v; v.f = f;
    unsigned r = v.u + 0x7FFFu + ((v.u >> 16) & 1u);   // RNE
    return (unsigned short)(r >> 16);
}
__device__ __forceinline__ float bf2f(unsigned short h) {
    union { unsigned u; float f; } v; v.u = ((unsigned)h) << 16;
    return v.f;
}

// setup: W2p = W2@Wfc, b2p = b2@Wfc + bfc, slab cursor init, slice work ctrs
__global__ void setup_kernel(const float* __restrict__ W2, const float* __restrict__ Wfc,
                             const float* __restrict__ b2, const float* __restrict__ bfc,
                             float* __restrict__ W2p, float* __restrict__ b2p,
                             int* __restrict__ cur_d, int* __restrict__ cur_s,
                             int* __restrict__ gwork, int nbuck) {
    int idx = blockIdx.x * blockDim.x + threadIdx.x;
    if (idx < nbuck) { cur_d[idx] = idx * SLAB; cur_s[idx] = idx * SLAB; }
    if (idx < 8) gwork[idx] = 0;
    if (idx < 128 * 40) {
        int k = idx / 40, c = idx - k * 40;
        const float* w2row = W2 + k * 128;
        float a = 0.f;
        #pragma unroll 8
        for (int j = 0; j < 128; ++j) a += w2row[j] * Wfc[j * 40 + c];
        W2p[idx] = a;
    } else if (idx < 129 * 40) {
        int c = idx - 128 * 40;
        float a = bfc[c];
        #pragma unroll 8
        for (int j = 0; j < 128; ++j) a += b2[j] * Wfc[j * 40 + c];
        b2p[c] = a;
    }
}

// ------------- single-pass partition with per-bucket slab reservation -------
__global__ __launch_bounds__(256) void scatter_res_kernel(
        const int* __restrict__ src, const int* __restrict__ dst,
        int* __restrict__ cur_d, int* __restrict__ cur_s,
        unsigned int* __restrict__ ppack, unsigned short* __restrict__ es_loc,
        int E) {
    __shared__ int hd[NB], hs[NB], bd[NB], bs[NB];
    const int tid = threadIdx.x;
    hd[tid] = 0; hs[tid] = 0;
    __syncthreads();
    const int base = blockIdx.x * CHUNK;
    const int end  = min(base + CHUNK, E);
    for (int e = base + tid; e < end; e += 256) {
        atomicAdd(&hd[((unsigned)dst[e]) >> 9], 1);
        atomicAdd(&hs[((unsigned)src[e]) >> 9], 1);
    }
    __syncthreads();
    int cd = hd[tid], cs = hs[tid];
    bd[tid] = cd ? atomicAdd(&cur_d[tid], cd) : 0;
    bs[tid] = cs ? atomicAdd(&cur_s[tid], cs) : 0;
    hd[tid] = 0; hs[tid] = 0;
    __syncthreads();
    for (int e = base + tid; e < end; e += 256) {
        int d = dst[e], s = src[e];
        unsigned bin_d = ((unsigned)d) >> 9;
        int pos = bd[bin_d] + atomicAdd(&hd[bin_d], 1);
        ppack[pos] = (((unsigned)d & 511u) << 17) | (unsigned)s;
        unsigned bin_s = ((unsigned)s) >> 9;
        int ps = bs[bin_s] + atomicAdd(&hs[bin_s], 1);
        es_loc[ps] = (unsigned short)(s & 511);
    }
}

// ------------- per-bucket fine pass for dst (slab ranges) -------------------
__global__ __launch_bounds__(256) void fine_dst_kernel(
        const unsigned int* __restrict__ ppack, const int* __restrict__ cur_d,
        int* __restrict__ deg_in, float* __restrict__ norm_in,
        int* __restrict__ row_ptr, int* __restrict__ csr_src, int N_) {
    __shared__ int h[512];
    __shared__ int psum[256];
    const int tid = threadIdx.x;
    const int b = blockIdx.x;
    const int start = b * SLAB;
    const int end   = cur_d[b];
    const int node0 = b * 512;

    h[tid] = 0; h[tid + 256] = 0;
    __syncthreads();
    for (int i = start + tid; i < end; i += 256)
        atomicAdd(&h[ppack[i] >> 17], 1);
    __syncthreads();

    int a0 = h[2 * tid], a1 = h[2 * tid + 1];
    int pair = a0 + a1;
    psum[tid] = pair;
    __syncthreads();
    for (int off = 1; off < 256; off <<= 1) {
        int t = (tid >= off) ? psum[tid - off] : 0;
        __syncthreads();
        psum[tid] += t;
        __syncthreads();
    }
    int base0 = psum[tid] - pair + start;   // slab-local CSR position

    int n0 = node0 + 2 * tid, n1 = n0 + 1;
    if (n0 < N_) {
        deg_in[n0]  = a0;
        row_ptr[n0] = base0;
        norm_in[n0] = rsqrtf((float)(a0 < 1 ? 1 : a0));
    }
    if (n1 < N_) {
        deg_in[n1]  = a1;
        row_ptr[n1] = base0 + a0;
        norm_in[n1] = rsqrtf((float)(a1 < 1 ? 1 : a1));
    }
    h[2 * tid]     = base0;
    h[2 * tid + 1] = base0 + a0;
    __syncthreads();

    for (int i = start + tid; i < end; i += 256) {
        unsigned int pk = ppack[i];
        int pos = atomicAdd(&h[pk >> 17], 1);
        csr_src[pos] = (int)(pk & 0x1FFFFu);
    }
}

// ------------- per-bucket fine pass for src (norm_out only) -----------------
__global__ __launch_bounds__(256) void fine_src_kernel(
        const unsigned short* __restrict__ es_loc, const int* __restrict__ cur_s,
        float* __restrict__ norm_out, int N_) {
    __shared__ int h[512];
    const int tid = threadIdx.x;
    const int b = blockIdx.x;
    const int start = b * SLAB;
    const int end   = cur_s[b];
    const int node0 = b * 512;

    h[tid] = 0; h[tid + 256] = 0;
    __syncthreads();
    for (int i = start + tid; i < end; i += 256)
        atomicAdd(&h[es_loc[i]], 1);
    __syncthreads();

    int n0 = node0 + tid, n1 = n0 + 256;
    if (n0 < N_) { int d = h[tid];       norm_out[n0] = rsqrtf((float)(d < 1 ? 1 : d)); }
    if (n1 < N_) { int d = h[tid + 256]; norm_out[n1] = rsqrtf((float)(d < 1 ? 1 : d)); }
}

// ---------------------------------------------------------------------------
// Y (fp16, SLICE-MAJOR [8][nrows][16]) = (X * scale[row]) @ W[128x128].
// ---------------------------------------------------------------------------
__global__ __launch_bounds__(256, 2) void gemm128(
        const float* __restrict__ X, const float* __restrict__ scale,
        const float* __restrict__ W, __half* __restrict__ Y, int nrows) {
    __shared__ unsigned short wsh[128 * 128];   // 32 KB, frag-ordered bf16 hi
    __shared__ unsigned short wsl[128 * 128];   // 32 KB, frag-ordered bf16 lo
    const int tid = threadIdx.x;

    for (int i = tid; i < 4096; i += 256) {
        int k  = i >> 5;
        int n0 = (i & 31) * 4;
        float4 wv = *(const float4*)(W + k * 128 + n0);
        int q = k >> 5, j = k & 7, lb = ((k >> 3) & 3) * 16;
        int tcol = n0 >> 4;
        int base = ((tcol * 4 + q) * 64) * 8 + j;
        float vals[4] = {wv.x, wv.y, wv.z, wv.w};
        #pragma unroll
        for (int c = 0; c < 4; ++c) {
            int l = lb + ((n0 + c) & 15);
            unsigned short h = f2bf(vals[c]);
            wsh[base + l * 8] = h;
            wsl[base + l * 8] = f2bf(vals[c] - bf2f(h));
        }
    }
    __syncthreads();

    const int lane = tid & 63;
    const int w    = tid >> 6;
    const int m    = lane & 15;
    const int quad = lane >> 4;
    const int rowBase = blockIdx.x * 128 + w * 32;

    bf16x8 Ah[2][4], Al[2][4];
    #pragma unroll
    for (int rt = 0; rt < 2; ++rt) {
        int r = rowBase + rt * 16 + m;
        float sc = (r < nrows) ? scale[r] : 0.f;
        const float* xr = X + (size_t)(r < nrows ? r : 0) * 128;
        #pragma unroll
        for (int q = 0; q < 4; ++q) {
            int k0 = q * 32 + quad * 8;
            float4 a = *(const float4*)(xr + k0);
            float4 bv = *(const float4*)(xr + k0 + 4);
            float v[8] = {a.x * sc, a.y * sc, a.z * sc, a.w * sc,
                          bv.x * sc, bv.y * sc, bv.z * sc, bv.w * sc};
            bf16x8 hi, lo;
            #pragma unroll
            for (int j = 0; j < 8; ++j) {
                unsigned short h = f2bf(v[j]);
                hi[j] = (short)h;
                lo[j] = (short)f2bf(v[j] - bf2f(h));
            }
            Ah[rt][q] = hi; Al[rt][q] = lo;
        }
    }

    f32x4 acc[2][8];
    #pragma unroll
    for (int rt = 0; rt < 2; ++rt)
        #pragma unroll
        for (int t = 0; t < 8; ++t)
            acc[rt][t] = (f32x4){0.f, 0.f, 0.f, 0.f};

    #pragma unroll
    for (int t = 0; t < 8; ++t) {
        #pragma unroll
        for (int q = 0; q < 4; ++q) {
            const int off = ((t * 4 + q) * 64 + lane) * 8;
            bf16x8 Bh = *(const bf16x8*)(wsh + off);
            bf16x8 Bl = *(const bf16x8*)(wsl + off);
            #pragma unroll
            for (int rt = 0; rt < 2; ++rt) {
                acc[rt][t] = __builtin_amdgcn_mfma_f32_16x16x32_bf16(Ah[rt][q], Bh, acc[rt][t], 0, 0, 0);
                acc[rt][t] = __builtin_amdgcn_mfma_f32_16x16x32_bf16(Ah[rt][q], Bl, acc[rt][t], 0, 0, 0);
                acc[rt][t] = __builtin_amdgcn_mfma_f32_16x16x32_bf16(Al[rt][q], Bh, acc[rt][t], 0, 0, 0);
            }
        }
    }

    // sliced epilogue: col = t*16 + m  ->  Y[t][r][m]
    #pragma unroll
    for (int rt = 0; rt < 2; ++rt) {
        int r0 = rowBase + rt * 16 + quad * 4;
        #pragma unroll
        for (int reg = 0; reg < 4; ++reg) {
            int r = r0 + reg;
            if (r >= nrows) continue;
            #pragma unroll
            for (int t = 0; t < 8; ++t)
                Y[((size_t)t * nrows + r) * 16 + m] = __float2half(acc[rt][t][reg]);
        }
    }
}

// ---------------------------------------------------------------------------
// G[n x 40] (fp16) = (H_sliced * scale[row]) @ Wp[128 x 40]  via MFMA.
// H is slice-major [8][n][16] fp16.
// ---------------------------------------------------------------------------
__global__ __launch_bounds__(256, 2) void gemm40(
        const __half* __restrict__ H, const float* __restrict__ scale,
        const float* __restrict__ Wp, __half* __restrict__ G, int n) {
    __shared__ unsigned short wsh[48 * 128];   // 12 KB, frag-ordered bf16 hi
    __shared__ unsigned short wsl[48 * 128];   // 12 KB, frag-ordered bf16 lo
    const int tid = threadIdx.x;

    for (int i = tid; i < 6144; i += 256) {
        int k  = i / 48;        // 0..127
        int nn = i - k * 48;    // 0..47
        float v = (nn < 40) ? Wp[k * 40 + nn] : 0.f;
        int t = nn >> 4, q = k >> 5, j = k & 7;
        int l = ((k >> 3) & 3) * 16 + (nn & 15);
        int base = ((t * 4 + q) * 64 + l) * 8 + j;
        unsigned short h = f2bf(v);
        wsh[base] = h;
        wsl[base] = f2bf(v - bf2f(h));
    }
    __syncthreads();

    const int lane = tid & 63;
    const int w    = tid >> 6;
    const int m    = lane & 15;
    const int quad = lane >> 4;
    const int rowBase = blockIdx.x * 128 + w * 32;

    bf16x8 Ah[2][4], Al[2][4];
    #pragma unroll
    for (int rt = 0; rt < 2; ++rt) {
        int r = rowBase + rt * 16 + m;
        float sc = (r < n) ? scale[r] : 0.f;
        const int rr = (r < n) ? r : 0;
        #pragma unroll
        for (int q = 0; q < 4; ++q) {
            int k0 = q * 32 + quad * 8;
            int g = k0 >> 4, o = k0 & 15;          // slice group, intra-slice col
            const __half* xr = H + ((size_t)g * n + rr) * 16 + o;
            half4 a = *(const half4*)(xr);
            half4 bv = *(const half4*)(xr + 4);
            float v[8] = {__half2float(a.x) * sc, __half2float(a.y) * sc,
                          __half2float(a.z) * sc, __half2float(a.w) * sc,
                          __half2float(bv.x) * sc, __half2float(bv.y) * sc,
                          __half2float(bv.z) * sc, __half2float(bv.w) * sc};
            bf16x8 hi, lo;
            #pragma unroll
            for (int j = 0; j < 8; ++j) {
                unsigned short h = f2bf(v[j]);
                hi[j] = (short)h;
                lo[j] = (short)f2bf(v[j] - bf2f(h));
            }
            Ah[rt][q] = hi; Al[rt][q] = lo;
        }
    }

    f32x4 acc[2][3];
    #pragma unroll
    for (int rt = 0; rt < 2; ++rt)
        #pragma unroll
        for (int t = 0; t < 3; ++t)
            acc[rt][t] = (f32x4){0.f, 0.f, 0.f, 0.f};

    #pragma unroll
    for (int t = 0; t < 3; ++t) {
        #pragma unroll
        for (int q = 0; q < 4; ++q) {
            const int off = ((t * 4 + q) * 64 + lane) * 8;
            bf16x8 Bh = *(const bf16x8*)(wsh + off);
            bf16x8 Bl = *(const bf16x8*)(wsl + off);
            #pragma unroll
            for (int rt = 0; rt < 2; ++rt) {
                acc[rt][t] = __builtin_amdgcn_mfma_f32_16x16x32_bf16(Ah[rt][q], Bh, acc[rt][t], 0, 0, 0);
                acc[rt][t] = __builtin_amdgcn_mfma_f32_16x16x32_bf16(Ah[rt][q], Bl, acc[rt][t], 0, 0, 0);
                acc[rt][t] = __builtin_amdgcn_mfma_f32_16x16x32_bf16(Al[rt][q], Bh, acc[rt][t], 0, 0, 0);
            }
        }
    }

    #pragma unroll
    for (int rt = 0; rt < 2; ++rt) {
        int r0 = rowBase + rt * 16 + quad * 4;
        #pragma unroll
        for (int reg = 0; reg < 4; ++reg) {
            int r = r0 + reg;
            if (r >= n) continue;
            __half* gr = G + (size_t)r * 40;
            #pragma unroll
            for (int t = 0; t < 3; ++t) {
                int col = t * 16 + m;
                if (col < 40) gr[col] = __float2half(acc[rt][t][reg]);
            }
        }
    }
}

// 128-dim gather, column-sliced with TRUE XCD affinity.
// H/out slice-major [8][n][16] fp16. Persistent blocks read their physical
// XCD id (HW_REG_XCC_ID, m09-verified) and drain the matching slice's work
// counter so XCD s only touches slice s (3.2 MB -> resident in its 4 MB L2).
// After own slice is exhausted, steal from others (correct under ANY
// block->XCD mapping; counters make each (slice, nodeblk) unit run once).
__global__ __launch_bounds__(256) void gather_kernel(
        const __half* __restrict__ H, const int* __restrict__ row_ptr,
        const int* __restrict__ deg, const int* __restrict__ csr_src,
        const float* __restrict__ norm_in, const float* __restrict__ b,
        __half* __restrict__ out, int* __restrict__ gwork, int n) {
    int xcd;
    asm volatile("s_getreg_b32 %0, hwreg(HW_REG_XCC_ID)" : "=s"(xcd));
    xcd &= 7;
    const int tid = threadIdx.x;
    const int ho  = (tid & 1) * 8;                // 0 or 8 within the slice
    const int nodeblks = (n + 127) >> 7;
    __shared__ int s_nb;

    for (int off = 0; off < 8; ++off) {
        const int slice = (xcd + off) & 7;
        const __half* Hs = H + (size_t)slice * n * 16;
        __half* Os = out + (size_t)slice * n * 16;
        const int c = slice * 16 + ho;            // global column (bias)
        const float4 b0  = *(const float4*)(b + c);
        const float4 b1v = *(const float4*)(b + c + 4);

        while (true) {
            __syncthreads();
            if (tid == 0) s_nb = atomicAdd(&gwork[slice], 1);
            __syncthreads();
            const int nb = s_nb;
            if (nb >= nodeblks) break;

            const int node = nb * 128 + (tid >> 1);
            if (node >= n) continue;

            const int start = row_ptr[node];
            const int cnt   = deg[node];
            float acc[8] = {0.f, 0.f, 0.f, 0.f, 0.f, 0.f, 0.f, 0.f};

            int j = 0;
            for (; j + 4 <= cnt; j += 4) {
                int s0 = csr_src[start + j];
                int s1 = csr_src[start + j + 1];
                int s2 = csr_src[start + j + 2];
                int s3 = csr_src[start + j + 3];
                half8 v0 = *(const half8*)(Hs + (size_t)s0 * 16 + ho);
                half8 v1 = *(const half8*)(Hs + (size_t)s1 * 16 + ho);
                half8 v2 = *(const half8*)(Hs + (size_t)s2 * 16 + ho);
                half8 v3 = *(const half8*)(Hs + (size_t)s3 * 16 + ho);
                #pragma unroll
                for (int k = 0; k < 8; ++k)
                    acc[k] += (__half2float(v0.h[k]) + __half2float(v1.h[k]))
                            + (__half2float(v2.h[k]) + __half2float(v3.h[k]));
            }
            for (; j < cnt; ++j) {
                int s0 = csr_src[start + j];
                half8 v0 = *(const half8*)(Hs + (size_t)s0 * 16 + ho);
                #pragma unroll
                for (int k = 0; k < 8; ++k) acc[k] += __half2float(v0.h[k]);
            }

            float ni = norm_in[node];
            half8 o;
            o.h[0] = __float2half(fmaxf(acc[0] * ni + b0.x, 0.f));
            o.h[1] = __float2half(fmaxf(acc[1] * ni + b0.y, 0.f));
            o.h[2] = __float2half(fmaxf(acc[2] * ni + b0.z, 0.f));
            o.h[3] = __float2half(fmaxf(acc[3] * ni + b0.w, 0.f));
            o.h[4] = __float2half(fmaxf(acc[4] * ni + b1v.x, 0.f));
            o.h[5] = __float2half(fmaxf(acc[5] * ni + b1v.y, 0.f));
            o.h[6] = __float2half(fmaxf(acc[6] * ni + b1v.z, 0.f));
            o.h[7] = __float2half(fmaxf(acc[7] * ni + b1v.w, 0.f));
            *(half8*)(Os + (size_t)node * 16 + ho) = o;
        }
    }
}

// 40-dim gather (fp16 in, fp32 out): out[node] = (sum G[src]) * ni + b2p
// 5 lanes per node, one half8 (16 B) each.
__global__ __launch_bounds__(256) void gather40_kernel(
        const __half* __restrict__ G, const int* __restrict__ row_ptr,
        const int* __restrict__ deg, const int* __restrict__ csr_src,
        const float* __restrict__ norm_in, const float* __restrict__ b2p,
        float* __restrict__ out, int n) {
    const int t = blockIdx.x * 256 + threadIdx.x;
    if (t >= n * 5) return;
    const int node = t / 5;
    const int c    = (t - node * 5) * 8;

    const int start = row_ptr[node];
    const int cnt   = deg[node];
    float acc[8] = {0.f, 0.f, 0.f, 0.f, 0.f, 0.f, 0.f, 0.f};

    int j = 0;
    for (; j + 4 <= cnt; j += 4) {
        int s0 = csr_src[start + j];
        int s1 = csr_src[start + j + 1];
        int s2 = csr_src[start + j + 2];
        int s3 = csr_src[start + j + 3];
        half8 v0 = *(const half8*)(G + (long long)s0 * 40 + c);
        half8 v1 = *(const half8*)(G + (long long)s1 * 40 + c);
        half8 v2 = *(const half8*)(G + (long long)s2 * 40 + c);
        half8 v3 = *(const half8*)(G + (long long)s3 * 40 + c);
        #pragma unroll
        for (int k = 0; k < 8; ++k)
            acc[k] += (__half2float(v0.h[k]) + __half2float(v1.h[k]))
                    + (__half2float(v2.h[k]) + __half2float(v3.h[k]));
    }
    for (; j < cnt; ++j) {
        int s0 = csr_src[start + j];
        half8 v0 = *(const half8*)(G + (long long)s0 * 40 + c);
        #pragma unroll
        for (int k = 0; k < 8; ++k) acc[k] += __half2float(v0.h[k]);
    }

    float ni = norm_in[node];
    float4 o0, o1;
    o0.x = acc[0] * ni + b2p[c + 0];
    o0.y = acc[1] * ni + b2p[c + 1];
    o0.z = acc[2] * ni + b2p[c + 2];
    o0.w = acc[3] * ni + b2p[c + 3];
    o1.x = acc[4] * ni + b2p[c + 4];
    o1.y = acc[5] * ni + b2p[c + 5];
    o1.z = acc[6] * ni + b2p[c + 6];
    o1.w = acc[7] * ni + b2p[c + 7];
    float* op = out + (long long)node * 40 + c;
    *(float4*)(op)     = o0;
    *(float4*)(op + 4) = o1;
}

extern "C" void kernel_launch(void* const* d_in, const int* in_sizes, int n_in,
                              void* d_out, int out_size, void* d_ws, size_t ws_size,
                              hipStream_t stream) {
    const float* x   = (const float*)d_in[0];
    const int*   ei  = (const int*)  d_in[1];
    const float* W1  = (const float*)d_in[2];
    const float* b1  = (const float*)d_in[3];
    const float* W2  = (const float*)d_in[4];
    const float* b2  = (const float*)d_in[5];
    const float* Wfc = (const float*)d_in[6];
    const float* bfc = (const float*)d_in[7];
    float* out = (float*)d_out;

    const int N = in_sizes[0] / 128;
    const int E = in_sizes[1] / 2;
    const int* src = ei;
    const int* dst = ei + E;

    const int nbuck = (N + 511) >> 9;                  // 196
    const int B1 = (E + CHUNK - 1) / CHUNK;            // 391 partition blocks

    char* p = (char*)d_ws;
    float* norm_out = (float*)p; p += (size_t)N * 4;
    float* norm_in  = (float*)p; p += (size_t)N * 4;
    float* bufA     = (float*)p; p += (size_t)N * 128 * 4;   // h1pre fp16, then G fp16
    float* bufB     = (float*)p; p += (size_t)N * 128 * 4;   // h1 fp16 (early: slabs)
    int*   deg_in   = (int*)p;   p += (size_t)N * 4;
    int*   row_ptr  = (int*)p;   p += (size_t)N * 4;
    int*   csr_src  = (int*)p;   p += (size_t)nbuck * SLAB * 4;   // slab-indexed CSR
    int*   cur_d    = (int*)p;   p += (size_t)1024 * 4;
    int*   cur_s    = (int*)p;   p += (size_t)1024 * 4;
    float* W2p      = (float*)p; p += (size_t)128 * 40 * 4;
    float* b2p      = (float*)p; p += (size_t)64 * 4;
    int*   gwork    = (int*)p;   p += (size_t)64 * 4;

    // partition slabs alias bufB (consumed before gather writes h1 there)
    unsigned int*   ppack  = (unsigned int*)bufB;
    unsigned short* es_loc = (unsigned short*)(ppack + (size_t)nbuck * SLAB);

    __half* h1pre = (__half*)bufA;   // [8][N][16] fp16 (slice-major)
    __half* G     = (__half*)bufA;   // N x 40  fp16 (reused after gather1)
    __half* h1    = (__half*)bufB;   // [8][N][16] fp16 (slice-major)

    const int T = 256;

    // setup (weight fold + cursor init + slice work counters)
    setup_kernel<<<(129 * 40 + T - 1) / T, T, 0, stream>>>(
        W2, Wfc, b2, bfc, W2p, b2p, cur_d, cur_s, gwork, nbuck);
    // partition + norms
    scatter_res_kernel<<<B1, T, 0, stream>>>(src, dst, cur_d, cur_s, ppack, es_loc, E);
    fine_dst_kernel<<<nbuck, T, 0, stream>>>(ppack, cur_d, deg_in, norm_in,
                                             row_ptr, csr_src, N);
    fine_src_kernel<<<nbuck, T, 0, stream>>>(es_loc, cur_s, norm_out, N);

    // layer 0: h1 = relu(gather(Xn @ W1) * ni + b1)   [MFMA bf16-split GEMM]
    const int gemm_grid = (N + 127) / 128;
    gemm128<<<gemm_grid, T, 0, stream>>>(x, norm_out, W1, h1pre, N);
    // persistent XCD-affine gather: 2048 blocks (~8/CU), work-stealing
    gather_kernel<<<2048, T, 0, stream>>>(h1pre, row_ptr, deg_in, csr_src,
                                          norm_in, b1, h1, gwork, N);
    // layer 1 + FC fused: out = gather((h1*no) @ W2p) * ni + b2p  [MFMA]
    gemm40<<<gemm_grid, T, 0, stream>>>(h1, norm_out, W2p, G, N);
    gather40_kernel<<<((size_t)N * 5 + T - 1) / T, T, 0, stream>>>(
        G, row_ptr, deg_in, csr_src, norm_in, b2p, out, N);
}

// Round 3
// 314.709 us; speedup vs baseline: 1.7634x; 1.7634x over previous
//
#include <hip/hip_runtime.h>
#include <hip/hip_fp16.h>

// ---------------------------------------------------------------------------
// GCN: 2x GraphConv (norm='both') + FC.  fp32 math, fp16 intermediates.
// R2..R8: 5943 -> 325 us (CSR gather, fold FC, MFMA GEMMs, fp16, no atomics).
// R9: reservation partition (323 us).
// R10: gather+gemm fusion REGRESSED (394 us): occupancy 68%->16%. Reverted.
// R11: gather1 16 lanes x half8; CHUNK 4096. 323 us.
// R12: column-sliced gather (blockIdx&7 "XCD affinity"). REGRESSED 351 us:
//      FETCH 178->153 MB only; blockIdx%8 is not an XCD map; 32B granules.
// R13: HW_REG_XCC_ID + persistent work-steal. REGRESSED 555 us: FETCH still
//      153 MB (csr stream thrashes the 4MB L2 even with true affinity;
//      per-XCD replication of shared data is structural) and the grab loop
//      + 32B granules collapsed issue rate (VALUBusy 7%). Theory abandoned.
// R14: revert to R11 structure. + Pad G rows 80B->128B (one aligned TCC line
//      per random gather40 access instead of 1.625) + merge fine_dst/fine_src
//      (one launch fewer). Gather stays the 3.6TB/s LLC-gather roofline.
// ---------------------------------------------------------------------------

#define CHUNK    4096   // edges per partition block
#define NB       256    // coarse buckets (node>>9; ceil(100000/512)=196)
#define SLAB     9216   // per-bucket slab capacity (mean 8163 + ~11 sigma)

typedef __attribute__((ext_vector_type(8))) short bf16x8;
typedef __attribute__((ext_vector_type(4))) float f32x4;

struct __align__(8)  half4 { __half x, y, z, w; };
struct __align__(16) half8 { __half h[8]; };

__device__ __forceinline__ unsigned short f2bf(float f) {
    union { float f; unsigned u; } v; v.f = f;
    unsigned r = v.u + 0x7FFFu + ((v.u >> 16) & 1u);   // RNE
    return (unsigned short)(r >> 16);
}
__device__ __forceinline__ float bf2f(unsigned short h) {
    union { unsigned u; float f; } v; v.u = ((unsigned)h) << 16;
    return v.f;
}

// setup: W2p = W2@Wfc, b2p = b2@Wfc + bfc, and slab cursor init
__global__ void setup_kernel(const float* __restrict__ W2, const float* __restrict__ Wfc,
                             const float* __restrict__ b2, const float* __restrict__ bfc,
                             float* __restrict__ W2p, float* __restrict__ b2p,
                             int* __restrict__ cur_d, int* __restrict__ cur_s, int nbuck) {
    int idx = blockIdx.x * blockDim.x + threadIdx.x;
    if (idx < nbuck) { cur_d[idx] = idx * SLAB; cur_s[idx] = idx * SLAB; }
    if (idx < 128 * 40) {
        int k = idx / 40, c = idx - k * 40;
        const float* w2row = W2 + k * 128;
        float a = 0.f;
        #pragma unroll 8
        for (int j = 0; j < 128; ++j) a += w2row[j] * Wfc[j * 40 + c];
        W2p[idx] = a;
    } else if (idx < 129 * 40) {
        int c = idx - 128 * 40;
        float a = bfc[c];
        #pragma unroll 8
        for (int j = 0; j < 128; ++j) a += b2[j] * Wfc[j * 40 + c];
        b2p[c] = a;
    }
}

// ------------- single-pass partition with per-bucket slab reservation -------
__global__ __launch_bounds__(256) void scatter_res_kernel(
        const int* __restrict__ src, const int* __restrict__ dst,
        int* __restrict__ cur_d, int* __restrict__ cur_s,
        unsigned int* __restrict__ ppack, unsigned short* __restrict__ es_loc,
        int E) {
    __shared__ int hd[NB], hs[NB], bd[NB], bs[NB];
    const int tid = threadIdx.x;
    hd[tid] = 0; hs[tid] = 0;
    __syncthreads();
    const int base = blockIdx.x * CHUNK;
    const int end  = min(base + CHUNK, E);
    for (int e = base + tid; e < end; e += 256) {
        atomicAdd(&hd[((unsigned)dst[e]) >> 9], 1);
        atomicAdd(&hs[((unsigned)src[e]) >> 9], 1);
    }
    __syncthreads();
    int cd = hd[tid], cs = hs[tid];
    bd[tid] = cd ? atomicAdd(&cur_d[tid], cd) : 0;
    bs[tid] = cs ? atomicAdd(&cur_s[tid], cs) : 0;
    hd[tid] = 0; hs[tid] = 0;
    __syncthreads();
    for (int e = base + tid; e < end; e += 256) {
        int d = dst[e], s = src[e];
        unsigned bin_d = ((unsigned)d) >> 9;
        int pos = bd[bin_d] + atomicAdd(&hd[bin_d], 1);
        ppack[pos] = (((unsigned)d & 511u) << 17) | (unsigned)s;
        unsigned bin_s = ((unsigned)s) >> 9;
        int ps = bs[bin_s] + atomicAdd(&hs[bin_s], 1);
        es_loc[ps] = (unsigned short)(s & 511);
    }
}

// ------------- per-bucket fine pass: dst (CSR) + src (norm_out) merged ------
__global__ __launch_bounds__(256) void fine_kernel(
        const unsigned int* __restrict__ ppack, const int* __restrict__ cur_d,
        const unsigned short* __restrict__ es_loc, const int* __restrict__ cur_s,
        int* __restrict__ deg_in, float* __restrict__ norm_in,
        int* __restrict__ row_ptr, int* __restrict__ csr_src,
        float* __restrict__ norm_out, int N_) {
    __shared__ int h[512];
    __shared__ int psum[256];
    const int tid = threadIdx.x;
    const int b = blockIdx.x;
    const int start = b * SLAB;
    const int node0 = b * 512;

    // ---- dst: histogram -> prefix -> CSR scatter ----
    const int end_d = cur_d[b];
    h[tid] = 0; h[tid + 256] = 0;
    __syncthreads();
    for (int i = start + tid; i < end_d; i += 256)
        atomicAdd(&h[ppack[i] >> 17], 1);
    __syncthreads();

    int a0 = h[2 * tid], a1 = h[2 * tid + 1];
    int pair = a0 + a1;
    psum[tid] = pair;
    __syncthreads();
    for (int off = 1; off < 256; off <<= 1) {
        int t = (tid >= off) ? psum[tid - off] : 0;
        __syncthreads();
        psum[tid] += t;
        __syncthreads();
    }
    int base0 = psum[tid] - pair + start;   // slab-local CSR position

    int n0 = node0 + 2 * tid, n1 = n0 + 1;
    if (n0 < N_) {
        deg_in[n0]  = a0;
        row_ptr[n0] = base0;
        norm_in[n0] = rsqrtf((float)(a0 < 1 ? 1 : a0));
    }
    if (n1 < N_) {
        deg_in[n1]  = a1;
        row_ptr[n1] = base0 + a0;
        norm_in[n1] = rsqrtf((float)(a1 < 1 ? 1 : a1));
    }
    h[2 * tid]     = base0;
    h[2 * tid + 1] = base0 + a0;
    __syncthreads();

    for (int i = start + tid; i < end_d; i += 256) {
        unsigned int pk = ppack[i];
        int pos = atomicAdd(&h[pk >> 17], 1);
        csr_src[pos] = (int)(pk & 0x1FFFFu);
    }
    __syncthreads();

    // ---- src: histogram -> norm_out ----
    const int end_s = cur_s[b];
    h[tid] = 0; h[tid + 256] = 0;
    __syncthreads();
    for (int i = start + tid; i < end_s; i += 256)
        atomicAdd(&h[es_loc[i]], 1);
    __syncthreads();

    int m0 = node0 + tid, m1 = m0 + 256;
    if (m0 < N_) { int d = h[tid];       norm_out[m0] = rsqrtf((float)(d < 1 ? 1 : d)); }
    if (m1 < N_) { int d = h[tid + 256]; norm_out[m1] = rsqrtf((float)(d < 1 ? 1 : d)); }
}

// ---------------------------------------------------------------------------
// Y[nrows x 128] (fp16) = (X * scale[row]) @ W[128x128]  via MFMA bf16 split.
// ---------------------------------------------------------------------------
__global__ __launch_bounds__(256, 2) void gemm128(
        const float* __restrict__ X, const float* __restrict__ scale,
        const float* __restrict__ W, __half* __restrict__ Y, int nrows) {
    __shared__ unsigned short wsh[128 * 128];   // 32 KB, frag-ordered bf16 hi
    __shared__ unsigned short wsl[128 * 128];   // 32 KB, frag-ordered bf16 lo
    const int tid = threadIdx.x;

    for (int i = tid; i < 4096; i += 256) {
        int k  = i >> 5;
        int n0 = (i & 31) * 4;
        float4 wv = *(const float4*)(W + k * 128 + n0);
        int q = k >> 5, j = k & 7, lb = ((k >> 3) & 3) * 16;
        int tcol = n0 >> 4;
        int base = ((tcol * 4 + q) * 64) * 8 + j;
        float vals[4] = {wv.x, wv.y, wv.z, wv.w};
        #pragma unroll
        for (int c = 0; c < 4; ++c) {
            int l = lb + ((n0 + c) & 15);
            unsigned short h = f2bf(vals[c]);
            wsh[base + l * 8] = h;
            wsl[base + l * 8] = f2bf(vals[c] - bf2f(h));
        }
    }
    __syncthreads();

    const int lane = tid & 63;
    const int w    = tid >> 6;
    const int m    = lane & 15;
    const int quad = lane >> 4;
    const int rowBase = blockIdx.x * 128 + w * 32;

    bf16x8 Ah[2][4], Al[2][4];
    #pragma unroll
    for (int rt = 0; rt < 2; ++rt) {
        int r = rowBase + rt * 16 + m;
        float sc = (r < nrows) ? scale[r] : 0.f;
        const float* xr = X + (size_t)(r < nrows ? r : 0) * 128;
        #pragma unroll
        for (int q = 0; q < 4; ++q) {
            int k0 = q * 32 + quad * 8;
            float4 a = *(const float4*)(xr + k0);
            float4 bv = *(const float4*)(xr + k0 + 4);
            float v[8] = {a.x * sc, a.y * sc, a.z * sc, a.w * sc,
                          bv.x * sc, bv.y * sc, bv.z * sc, bv.w * sc};
            bf16x8 hi, lo;
            #pragma unroll
            for (int j = 0; j < 8; ++j) {
                unsigned short h = f2bf(v[j]);
                hi[j] = (short)h;
                lo[j] = (short)f2bf(v[j] - bf2f(h));
            }
            Ah[rt][q] = hi; Al[rt][q] = lo;
        }
    }

    f32x4 acc[2][8];
    #pragma unroll
    for (int rt = 0; rt < 2; ++rt)
        #pragma unroll
        for (int t = 0; t < 8; ++t)
            acc[rt][t] = (f32x4){0.f, 0.f, 0.f, 0.f};

    #pragma unroll
    for (int t = 0; t < 8; ++t) {
        #pragma unroll
        for (int q = 0; q < 4; ++q) {
            const int off = ((t * 4 + q) * 64 + lane) * 8;
            bf16x8 Bh = *(const bf16x8*)(wsh + off);
            bf16x8 Bl = *(const bf16x8*)(wsl + off);
            #pragma unroll
            for (int rt = 0; rt < 2; ++rt) {
                acc[rt][t] = __builtin_amdgcn_mfma_f32_16x16x32_bf16(Ah[rt][q], Bh, acc[rt][t], 0, 0, 0);
                acc[rt][t] = __builtin_amdgcn_mfma_f32_16x16x32_bf16(Ah[rt][q], Bl, acc[rt][t], 0, 0, 0);
                acc[rt][t] = __builtin_amdgcn_mfma_f32_16x16x32_bf16(Al[rt][q], Bh, acc[rt][t], 0, 0, 0);
            }
        }
    }

    #pragma unroll
    for (int rt = 0; rt < 2; ++rt) {
        int r0 = rowBase + rt * 16 + quad * 4;
        #pragma unroll
        for (int reg = 0; reg < 4; ++reg) {
            int r = r0 + reg;
            if (r >= nrows) continue;
            __half* yr = Y + (size_t)r * 128 + m;
            #pragma unroll
            for (int t = 0; t < 8; ++t)
                yr[t * 16] = __float2half(acc[rt][t][reg]);
        }
    }
}

// ---------------------------------------------------------------------------
// G (fp16, PADDED stride 64) = (H[n x 128 fp16] * scale[row]) @ Wp[128 x 40].
// Row pad 80B->128B: each random gather40 access is exactly one TCC line.
// ---------------------------------------------------------------------------
__global__ __launch_bounds__(256, 2) void gemm40(
        const __half* __restrict__ H, const float* __restrict__ scale,
        const float* __restrict__ Wp, __half* __restrict__ G, int n) {
    __shared__ unsigned short wsh[48 * 128];   // 12 KB, frag-ordered bf16 hi
    __shared__ unsigned short wsl[48 * 128];   // 12 KB, frag-ordered bf16 lo
    const int tid = threadIdx.x;

    for (int i = tid; i < 6144; i += 256) {
        int k  = i / 48;        // 0..127
        int nn = i - k * 48;    // 0..47
        float v = (nn < 40) ? Wp[k * 40 + nn] : 0.f;
        int t = nn >> 4, q = k >> 5, j = k & 7;
        int l = ((k >> 3) & 3) * 16 + (nn & 15);
        int base = ((t * 4 + q) * 64 + l) * 8 + j;
        unsigned short h = f2bf(v);
        wsh[base] = h;
        wsl[base] = f2bf(v - bf2f(h));
    }
    __syncthreads();

    const int lane = tid & 63;
    const int w    = tid >> 6;
    const int m    = lane & 15;
    const int quad = lane >> 4;
    const int rowBase = blockIdx.x * 128 + w * 32;

    bf16x8 Ah[2][4], Al[2][4];
    #pragma unroll
    for (int rt = 0; rt < 2; ++rt) {
        int r = rowBase + rt * 16 + m;
        float sc = (r < n) ? scale[r] : 0.f;
        const __half* xr = H + (size_t)(r < n ? r : 0) * 128;
        #pragma unroll
        for (int q = 0; q < 4; ++q) {
            int k0 = q * 32 + quad * 8;
            half4 a = *(const half4*)(xr + k0);
            half4 bv = *(const half4*)(xr + k0 + 4);
            float v[8] = {__half2float(a.x) * sc, __half2float(a.y) * sc,
                          __half2float(a.z) * sc, __half2float(a.w) * sc,
                          __half2float(bv.x) * sc, __half2float(bv.y) * sc,
                          __half2float(bv.z) * sc, __half2float(bv.w) * sc};
            bf16x8 hi, lo;
            #pragma unroll
            for (int j = 0; j < 8; ++j) {
                unsigned short h = f2bf(v[j]);
                hi[j] = (short)h;
                lo[j] = (short)f2bf(v[j] - bf2f(h));
            }
            Ah[rt][q] = hi; Al[rt][q] = lo;
        }
    }

    f32x4 acc[2][3];
    #pragma unroll
    for (int rt = 0; rt < 2; ++rt)
        #pragma unroll
        for (int t = 0; t < 3; ++t)
            acc[rt][t] = (f32x4){0.f, 0.f, 0.f, 0.f};

    #pragma unroll
    for (int t = 0; t < 3; ++t) {
        #pragma unroll
        for (int q = 0; q < 4; ++q) {
            const int off = ((t * 4 + q) * 64 + lane) * 8;
            bf16x8 Bh = *(const bf16x8*)(wsh + off);
            bf16x8 Bl = *(const bf16x8*)(wsl + off);
            #pragma unroll
            for (int rt = 0; rt < 2; ++rt) {
                acc[rt][t] = __builtin_amdgcn_mfma_f32_16x16x32_bf16(Ah[rt][q], Bh, acc[rt][t], 0, 0, 0);
                acc[rt][t] = __builtin_amdgcn_mfma_f32_16x16x32_bf16(Ah[rt][q], Bl, acc[rt][t], 0, 0, 0);
                acc[rt][t] = __builtin_amdgcn_mfma_f32_16x16x32_bf16(Al[rt][q], Bh, acc[rt][t], 0, 0, 0);
            }
        }
    }

    #pragma unroll
    for (int rt = 0; rt < 2; ++rt) {
        int r0 = rowBase + rt * 16 + quad * 4;
        #pragma unroll
        for (int reg = 0; reg < 4; ++reg) {
            int r = r0 + reg;
            if (r >= n) continue;
            __half* gr = G + (size_t)r * 64;    // padded stride
            #pragma unroll
            for (int t = 0; t < 3; ++t) {
                int col = t * 16 + m;
                if (col < 40) gr[col] = __float2half(acc[rt][t][reg]);
            }
        }
    }
}

// 128-dim gather (fp16 in, fp16 out): h1[node] = relu((sum H[src]) * ni + b)
// 16 lanes per node, one half8 (16 B) per lane; 16 nodes per 256-thread block.
__global__ __launch_bounds__(256) void gather_kernel(
        const __half* __restrict__ H, const int* __restrict__ row_ptr,
        const int* __restrict__ deg, const int* __restrict__ csr_src,
        const float* __restrict__ norm_in, const float* __restrict__ b,
        __half* __restrict__ out, int n) {
    const int tid  = threadIdx.x;
    const int node = blockIdx.x * 16 + (tid >> 4);
    const int c    = (tid & 15) * 8;
    if (node >= n) return;

    const int start = row_ptr[node];
    const int cnt   = deg[node];
    float acc[8] = {0.f, 0.f, 0.f, 0.f, 0.f, 0.f, 0.f, 0.f};

    int j = 0;
    for (; j + 4 <= cnt; j += 4) {
        int s0 = csr_src[start + j];
        int s1 = csr_src[start + j + 1];
        int s2 = csr_src[start + j + 2];
        int s3 = csr_src[start + j + 3];
        half8 v0 = *(const half8*)(H + (long long)s0 * 128 + c);
        half8 v1 = *(const half8*)(H + (long long)s1 * 128 + c);
        half8 v2 = *(const half8*)(H + (long long)s2 * 128 + c);
        half8 v3 = *(const half8*)(H + (long long)s3 * 128 + c);
        #pragma unroll
        for (int k = 0; k < 8; ++k)
            acc[k] += (__half2float(v0.h[k]) + __half2float(v1.h[k]))
                    + (__half2float(v2.h[k]) + __half2float(v3.h[k]));
    }
    for (; j < cnt; ++j) {
        int s0 = csr_src[start + j];
        half8 v0 = *(const half8*)(H + (long long)s0 * 128 + c);
        #pragma unroll
        for (int k = 0; k < 8; ++k) acc[k] += __half2float(v0.h[k]);
    }

    float ni = norm_in[node];
    float4 b0 = *(const float4*)(b + c);
    float4 b1v = *(const float4*)(b + c + 4);
    half8 o;
    o.h[0] = __float2half(fmaxf(acc[0] * ni + b0.x, 0.f));
    o.h[1] = __float2half(fmaxf(acc[1] * ni + b0.y, 0.f));
    o.h[2] = __float2half(fmaxf(acc[2] * ni + b0.z, 0.f));
    o.h[3] = __float2half(fmaxf(acc[3] * ni + b0.w, 0.f));
    o.h[4] = __float2half(fmaxf(acc[4] * ni + b1v.x, 0.f));
    o.h[5] = __float2half(fmaxf(acc[5] * ni + b1v.y, 0.f));
    o.h[6] = __float2half(fmaxf(acc[6] * ni + b1v.z, 0.f));
    o.h[7] = __float2half(fmaxf(acc[7] * ni + b1v.w, 0.f));
    *(half8*)(out + (long long)node * 128 + c) = o;
}

// 40-dim gather (fp16 in, PADDED stride 64; fp32 out): out = (sum G[src])*ni + b2p
// 5 lanes per node, one half8 (16 B) each.
__global__ __launch_bounds__(256) void gather40_kernel(
        const __half* __restrict__ G, const int* __restrict__ row_ptr,
        const int* __restrict__ deg, const int* __restrict__ csr_src,
        const float* __restrict__ norm_in, const float* __restrict__ b2p,
        float* __restrict__ out, int n) {
    const int t = blockIdx.x * 256 + threadIdx.x;
    if (t >= n * 5) return;
    const int node = t / 5;
    const int c    = (t - node * 5) * 8;

    const int start = row_ptr[node];
    const int cnt   = deg[node];
    float acc[8] = {0.f, 0.f, 0.f, 0.f, 0.f, 0.f, 0.f, 0.f};

    int j = 0;
    for (; j + 4 <= cnt; j += 4) {
        int s0 = csr_src[start + j];
        int s1 = csr_src[start + j + 1];
        int s2 = csr_src[start + j + 2];
        int s3 = csr_src[start + j + 3];
        half8 v0 = *(const half8*)(G + (long long)s0 * 64 + c);
        half8 v1 = *(const half8*)(G + (long long)s1 * 64 + c);
        half8 v2 = *(const half8*)(G + (long long)s2 * 64 + c);
        half8 v3 = *(const half8*)(G + (long long)s3 * 64 + c);
        #pragma unroll
        for (int k = 0; k < 8; ++k)
            acc[k] += (__half2float(v0.h[k]) + __half2float(v1.h[k]))
                    + (__half2float(v2.h[k]) + __half2float(v3.h[k]));
    }
    for (; j < cnt; ++j) {
        int s0 = csr_src[start + j];
        half8 v0 = *(const half8*)(G + (long long)s0 * 64 + c);
        #pragma unroll
        for (int k = 0; k < 8; ++k) acc[k] += __half2float(v0.h[k]);
    }

    float ni = norm_in[node];
    float4 o0, o1;
    o0.x = acc[0] * ni + b2p[c + 0];
    o0.y = acc[1] * ni + b2p[c + 1];
    o0.z = acc[2] * ni + b2p[c + 2];
    o0.w = acc[3] * ni + b2p[c + 3];
    o1.x = acc[4] * ni + b2p[c + 4];
    o1.y = acc[5] * ni + b2p[c + 5];
    o1.z = acc[6] * ni + b2p[c + 6];
    o1.w = acc[7] * ni + b2p[c + 7];
    float* op = out + (long long)node * 40 + c;
    *(float4*)(op)     = o0;
    *(float4*)(op + 4) = o1;
}

extern "C" void kernel_launch(void* const* d_in, const int* in_sizes, int n_in,
                              void* d_out, int out_size, void* d_ws, size_t ws_size,
                              hipStream_t stream) {
    const float* x   = (const float*)d_in[0];
    const int*   ei  = (const int*)  d_in[1];
    const float* W1  = (const float*)d_in[2];
    const float* b1  = (const float*)d_in[3];
    const float* W2  = (const float*)d_in[4];
    const float* b2  = (const float*)d_in[5];
    const float* Wfc = (const float*)d_in[6];
    const float* bfc = (const float*)d_in[7];
    float* out = (float*)d_out;

    const int N = in_sizes[0] / 128;
    const int E = in_sizes[1] / 2;
    const int* src = ei;
    const int* dst = ei + E;

    const int nbuck = (N + 511) >> 9;                  // 196
    const int B1 = (E + CHUNK - 1) / CHUNK;            // 391 partition blocks

    char* p = (char*)d_ws;
    float* norm_out = (float*)p; p += (size_t)N * 4;
    float* norm_in  = (float*)p; p += (size_t)N * 4;
    float* bufA     = (float*)p; p += (size_t)N * 128 * 4;   // h1pre fp16, then G fp16
    float* bufB     = (float*)p; p += (size_t)N * 128 * 4;   // h1 fp16 (early: slabs)
    int*   deg_in   = (int*)p;   p += (size_t)N * 4;
    int*   row_ptr  = (int*)p;   p += (size_t)N * 4;
    int*   csr_src  = (int*)p;   p += (size_t)nbuck * SLAB * 4;   // slab-indexed CSR
    int*   cur_d    = (int*)p;   p += (size_t)1024 * 4;
    int*   cur_s    = (int*)p;   p += (size_t)1024 * 4;
    float* W2p      = (float*)p; p += (size_t)128 * 40 * 4;
    float* b2p      = (float*)p; p += (size_t)64 * 4;

    // partition slabs alias bufB (consumed before gather writes h1 there)
    unsigned int*   ppack  = (unsigned int*)bufB;
    unsigned short* es_loc = (unsigned short*)(ppack + (size_t)nbuck * SLAB);

    __half* h1pre = (__half*)bufA;   // N x 128 fp16
    __half* G     = (__half*)bufA;   // N x 64 fp16 PADDED (reused after gather1)
    __half* h1    = (__half*)bufB;   // N x 128 fp16

    const int T = 256;

    // setup (weight fold + cursor init)
    setup_kernel<<<(129 * 40 + T - 1) / T, T, 0, stream>>>(
        W2, Wfc, b2, bfc, W2p, b2p, cur_d, cur_s, nbuck);
    // partition + norms (merged fine pass)
    scatter_res_kernel<<<B1, T, 0, stream>>>(src, dst, cur_d, cur_s, ppack, es_loc, E);
    fine_kernel<<<nbuck, T, 0, stream>>>(ppack, cur_d, es_loc, cur_s,
                                         deg_in, norm_in, row_ptr, csr_src,
                                         norm_out, N);

    // layer 0: h1 = relu(gather(Xn @ W1) * ni + b1)   [MFMA bf16-split GEMM]
    const int gemm_grid = (N + 127) / 128;
    gemm128<<<gemm_grid, T, 0, stream>>>(x, norm_out, W1, h1pre, N);
    const int gather_grid = (N + 15) / 16;
    gather_kernel<<<gather_grid, T, 0, stream>>>(h1pre, row_ptr, deg_in, csr_src,
                                                 norm_in, b1, h1, N);
    // layer 1 + FC fused: out = gather((h1*no) @ W2p) * ni + b2p  [MFMA]
    gemm40<<<gemm_grid, T, 0, stream>>>(h1, norm_out, W2p, G, N);
    gather40_kernel<<<((size_t)N * 5 + T - 1) / T, T, 0, stream>>>(
        G, row_ptr, deg_in, csr_src, norm_in, b2p, out, N);
}

// Round 4
// 297.865 us; speedup vs baseline: 1.8631x; 1.0565x over previous
//
#include <hip/hip_runtime.h>
#include <hip/hip_fp16.h>

// ---------------------------------------------------------------------------
// GCN: 2x GraphConv (norm='both') + FC.  fp32 math, fp16 intermediates.
// R2..R8: 5943 -> 325 us (CSR gather, fold FC, MFMA GEMMs, fp16, no atomics).
// R9: reservation partition (323 us).
// R10: gather+gemm fusion REGRESSED (394 us): occupancy 68%->16%. Reverted.
// R11: gather1 16 lanes x half8; CHUNK 4096. 323 us.
// R12/R13: XCD-affinity sliced gather (blockIdx&7, then HW_REG_XCC_ID +
//      work-steal). Both REGRESSED (351/555 us): FETCH stuck ~153 MB; per-XCD
//      L2 replication of shared tables is structural. Theory abandoned.
// R14: revert to R11 + pad G rows 80B->128B + merged fine pass. 314.7 us.
// R15: gemm128 exposed at 59 us (roofline ~15): 64KB LDS -> 2 blocks/CU (25%
//      occ) + every block refetches & reconverts W (800 VALU/thread) + 2
//      barriers. Fix: convert W1/W2p to frag-ordered bf16-split arrays ONCE
//      in setup; GEMMs load B-frags straight from global (coalesced 16B/lane,
//      L2-hot). No LDS, no syncs. launch_bounds (256,3)/(256,4).
// ---------------------------------------------------------------------------

#define CHUNK    4096   // edges per partition block
#define NB       256    // coarse buckets (node>>9; ceil(100000/512)=196)
#define SLAB     9216   // per-bucket slab capacity (mean 8163 + ~11 sigma)

typedef __attribute__((ext_vector_type(8))) short bf16x8;
typedef __attribute__((ext_vector_type(4))) float f32x4;

struct __align__(8)  half4 { __half x, y, z, w; };
struct __align__(16) half8 { __half h[8]; };

__device__ __forceinline__ unsigned short f2bf(float f) {
    union { float f; unsigned u; } v; v.f = f;
    unsigned r = v.u + 0x7FFFu + ((v.u >> 16) & 1u);   // RNE
    return (unsigned short)(r >> 16);
}
__device__ __forceinline__ float bf2f(unsigned short h) {
    union { unsigned u; float f; } v; v.u = ((unsigned)h) << 16;
    return v.f;
}

// ---------------------------------------------------------------------------
// setup: cursors, W1 -> frag-ordered bf16-split (Wh1/Wl1, 16384 each),
// W2p = W2@Wfc folded+converted (Wh2/Wl2, 48x128 = 6144 each, cols>=40 zero),
// b2p = b2@Wfc + bfc.
// ---------------------------------------------------------------------------
__global__ void setup_kernel(const float* __restrict__ W1, const float* __restrict__ W2,
                             const float* __restrict__ Wfc,
                             const float* __restrict__ b2, const float* __restrict__ bfc,
                             unsigned short* __restrict__ Wh1, unsigned short* __restrict__ Wl1,
                             unsigned short* __restrict__ Wh2, unsigned short* __restrict__ Wl2,
                             float* __restrict__ b2p,
                             int* __restrict__ cur_d, int* __restrict__ cur_s, int nbuck) {
    int idx = blockIdx.x * blockDim.x + threadIdx.x;
    if (idx < nbuck) { cur_d[idx] = idx * SLAB; cur_s[idx] = idx * SLAB; }

    if (idx < 16384) {
        // W1[k][nn] -> frag pos for gemm128
        int k = idx >> 7, nn = idx & 127;
        float v = W1[idx];
        int q = k >> 5, j = k & 7, lb = ((k >> 3) & 3) * 16;
        int tcol = nn >> 4;
        int l = lb + (nn & 15);
        int pos = ((tcol * 4 + q) * 64 + l) * 8 + j;
        unsigned short h = f2bf(v);
        Wh1[pos] = h;
        Wl1[pos] = f2bf(v - bf2f(h));
    } else if (idx < 16384 + 6144) {
        // W2p[k][nn] = dot(W2 row k, Wfc col nn) -> frag pos for gemm40
        int i2 = idx - 16384;
        int k = i2 / 48, nn = i2 - k * 48;
        float v = 0.f;
        if (nn < 40) {
            const float* w2row = W2 + k * 128;
            #pragma unroll 8
            for (int jj = 0; jj < 128; ++jj) v += w2row[jj] * Wfc[jj * 40 + nn];
        }
        int t = nn >> 4, q = k >> 5, j = k & 7;
        int l = ((k >> 3) & 3) * 16 + (nn & 15);
        int pos = ((t * 4 + q) * 64 + l) * 8 + j;
        unsigned short h = f2bf(v);
        Wh2[pos] = h;
        Wl2[pos] = f2bf(v - bf2f(h));
    } else if (idx < 16384 + 6144 + 40) {
        int c = idx - (16384 + 6144);
        float a = bfc[c];
        #pragma unroll 8
        for (int j = 0; j < 128; ++j) a += b2[j] * Wfc[j * 40 + c];
        b2p[c] = a;
    }
}

// ------------- single-pass partition with per-bucket slab reservation -------
__global__ __launch_bounds__(256) void scatter_res_kernel(
        const int* __restrict__ src, const int* __restrict__ dst,
        int* __restrict__ cur_d, int* __restrict__ cur_s,
        unsigned int* __restrict__ ppack, unsigned short* __restrict__ es_loc,
        int E) {
    __shared__ int hd[NB], hs[NB], bd[NB], bs[NB];
    const int tid = threadIdx.x;
    hd[tid] = 0; hs[tid] = 0;
    __syncthreads();
    const int base = blockIdx.x * CHUNK;
    const int end  = min(base + CHUNK, E);
    for (int e = base + tid; e < end; e += 256) {
        atomicAdd(&hd[((unsigned)dst[e]) >> 9], 1);
        atomicAdd(&hs[((unsigned)src[e]) >> 9], 1);
    }
    __syncthreads();
    int cd = hd[tid], cs = hs[tid];
    bd[tid] = cd ? atomicAdd(&cur_d[tid], cd) : 0;
    bs[tid] = cs ? atomicAdd(&cur_s[tid], cs) : 0;
    hd[tid] = 0; hs[tid] = 0;
    __syncthreads();
    for (int e = base + tid; e < end; e += 256) {
        int d = dst[e], s = src[e];
        unsigned bin_d = ((unsigned)d) >> 9;
        int pos = bd[bin_d] + atomicAdd(&hd[bin_d], 1);
        ppack[pos] = (((unsigned)d & 511u) << 17) | (unsigned)s;
        unsigned bin_s = ((unsigned)s) >> 9;
        int ps = bs[bin_s] + atomicAdd(&hs[bin_s], 1);
        es_loc[ps] = (unsigned short)(s & 511);
    }
}

// ------------- per-bucket fine pass: dst (CSR) + src (norm_out) merged ------
__global__ __launch_bounds__(256) void fine_kernel(
        const unsigned int* __restrict__ ppack, const int* __restrict__ cur_d,
        const unsigned short* __restrict__ es_loc, const int* __restrict__ cur_s,
        int* __restrict__ deg_in, float* __restrict__ norm_in,
        int* __restrict__ row_ptr, int* __restrict__ csr_src,
        float* __restrict__ norm_out, int N_) {
    __shared__ int h[512];
    __shared__ int psum[256];
    const int tid = threadIdx.x;
    const int b = blockIdx.x;
    const int start = b * SLAB;
    const int node0 = b * 512;

    // ---- dst: histogram -> prefix -> CSR scatter ----
    const int end_d = cur_d[b];
    h[tid] = 0; h[tid + 256] = 0;
    __syncthreads();
    for (int i = start + tid; i < end_d; i += 256)
        atomicAdd(&h[ppack[i] >> 17], 1);
    __syncthreads();

    int a0 = h[2 * tid], a1 = h[2 * tid + 1];
    int pair = a0 + a1;
    psum[tid] = pair;
    __syncthreads();
    for (int off = 1; off < 256; off <<= 1) {
        int t = (tid >= off) ? psum[tid - off] : 0;
        __syncthreads();
        psum[tid] += t;
        __syncthreads();
    }
    int base0 = psum[tid] - pair + start;   // slab-local CSR position

    int n0 = node0 + 2 * tid, n1 = n0 + 1;
    if (n0 < N_) {
        deg_in[n0]  = a0;
        row_ptr[n0] = base0;
        norm_in[n0] = rsqrtf((float)(a0 < 1 ? 1 : a0));
    }
    if (n1 < N_) {
        deg_in[n1]  = a1;
        row_ptr[n1] = base0 + a0;
        norm_in[n1] = rsqrtf((float)(a1 < 1 ? 1 : a1));
    }
    h[2 * tid]     = base0;
    h[2 * tid + 1] = base0 + a0;
    __syncthreads();

    for (int i = start + tid; i < end_d; i += 256) {
        unsigned int pk = ppack[i];
        int pos = atomicAdd(&h[pk >> 17], 1);
        csr_src[pos] = (int)(pk & 0x1FFFFu);
    }
    __syncthreads();

    // ---- src: histogram -> norm_out ----
    const int end_s = cur_s[b];
    h[tid] = 0; h[tid + 256] = 0;
    __syncthreads();
    for (int i = start + tid; i < end_s; i += 256)
        atomicAdd(&h[es_loc[i]], 1);
    __syncthreads();

    int m0 = node0 + tid, m1 = m0 + 256;
    if (m0 < N_) { int d = h[tid];       norm_out[m0] = rsqrtf((float)(d < 1 ? 1 : d)); }
    if (m1 < N_) { int d = h[tid + 256]; norm_out[m1] = rsqrtf((float)(d < 1 ? 1 : d)); }
}

// ---------------------------------------------------------------------------
// Y[nrows x 128] (fp16) = (X * scale[row]) @ W1  via MFMA bf16 split.
// B-frags from preconverted global Wh/Wl (L2-hot, coalesced 16B/lane).
// No LDS, no barriers -> VGPR-bound occupancy.
// ---------------------------------------------------------------------------
__global__ __launch_bounds__(256, 3) void gemm128(
        const float* __restrict__ X, const float* __restrict__ scale,
        const unsigned short* __restrict__ Wh, const unsigned short* __restrict__ Wl,
        __half* __restrict__ Y, int nrows) {
    const int tid  = threadIdx.x;
    const int lane = tid & 63;
    const int w    = tid >> 6;
    const int m    = lane & 15;
    const int quad = lane >> 4;
    const int rowBase = blockIdx.x * 128 + w * 32;

    bf16x8 Ah[2][4], Al[2][4];
    #pragma unroll
    for (int rt = 0; rt < 2; ++rt) {
        int r = rowBase + rt * 16 + m;
        float sc = (r < nrows) ? scale[r] : 0.f;
        const float* xr = X + (size_t)(r < nrows ? r : 0) * 128;
        #pragma unroll
        for (int q = 0; q < 4; ++q) {
            int k0 = q * 32 + quad * 8;
            float4 a = *(const float4*)(xr + k0);
            float4 bv = *(const float4*)(xr + k0 + 4);
            float v[8] = {a.x * sc, a.y * sc, a.z * sc, a.w * sc,
                          bv.x * sc, bv.y * sc, bv.z * sc, bv.w * sc};
            bf16x8 hi, lo;
            #pragma unroll
            for (int j = 0; j < 8; ++j) {
                unsigned short h = f2bf(v[j]);
                hi[j] = (short)h;
                lo[j] = (short)f2bf(v[j] - bf2f(h));
            }
            Ah[rt][q] = hi; Al[rt][q] = lo;
        }
    }

    f32x4 acc[2][8];
    #pragma unroll
    for (int rt = 0; rt < 2; ++rt)
        #pragma unroll
        for (int t = 0; t < 8; ++t)
            acc[rt][t] = (f32x4){0.f, 0.f, 0.f, 0.f};

    #pragma unroll
    for (int t = 0; t < 8; ++t) {
        #pragma unroll
        for (int q = 0; q < 4; ++q) {
            const int off = ((t * 4 + q) * 64 + lane) * 8;
            bf16x8 Bh = *(const bf16x8*)(Wh + off);
            bf16x8 Bl = *(const bf16x8*)(Wl + off);
            #pragma unroll
            for (int rt = 0; rt < 2; ++rt) {
                acc[rt][t] = __builtin_amdgcn_mfma_f32_16x16x32_bf16(Ah[rt][q], Bh, acc[rt][t], 0, 0, 0);
                acc[rt][t] = __builtin_amdgcn_mfma_f32_16x16x32_bf16(Ah[rt][q], Bl, acc[rt][t], 0, 0, 0);
                acc[rt][t] = __builtin_amdgcn_mfma_f32_16x16x32_bf16(Al[rt][q], Bh, acc[rt][t], 0, 0, 0);
            }
        }
    }

    #pragma unroll
    for (int rt = 0; rt < 2; ++rt) {
        int r0 = rowBase + rt * 16 + quad * 4;
        #pragma unroll
        for (int reg = 0; reg < 4; ++reg) {
            int r = r0 + reg;
            if (r >= nrows) continue;
            __half* yr = Y + (size_t)r * 128 + m;
            #pragma unroll
            for (int t = 0; t < 8; ++t)
                yr[t * 16] = __float2half(acc[rt][t][reg]);
        }
    }
}

// ---------------------------------------------------------------------------
// G (fp16, PADDED stride 64) = (H[n x 128 fp16] * scale[row]) @ W2p.
// B-frags from preconverted global Wh2/Wl2 (48x128, cols>=40 zero).
// ---------------------------------------------------------------------------
__global__ __launch_bounds__(256, 4) void gemm40(
        const __half* __restrict__ H, const float* __restrict__ scale,
        const unsigned short* __restrict__ Wh, const unsigned short* __restrict__ Wl,
        __half* __restrict__ G, int n) {
    const int tid  = threadIdx.x;
    const int lane = tid & 63;
    const int w    = tid >> 6;
    const int m    = lane & 15;
    const int quad = lane >> 4;
    const int rowBase = blockIdx.x * 128 + w * 32;

    bf16x8 Ah[2][4], Al[2][4];
    #pragma unroll
    for (int rt = 0; rt < 2; ++rt) {
        int r = rowBase + rt * 16 + m;
        float sc = (r < n) ? scale[r] : 0.f;
        const __half* xr = H + (size_t)(r < n ? r : 0) * 128;
        #pragma unroll
        for (int q = 0; q < 4; ++q) {
            int k0 = q * 32 + quad * 8;
            half4 a = *(const half4*)(xr + k0);
            half4 bv = *(const half4*)(xr + k0 + 4);
            float v[8] = {__half2float(a.x) * sc, __half2float(a.y) * sc,
                          __half2float(a.z) * sc, __half2float(a.w) * sc,
                          __half2float(bv.x) * sc, __half2float(bv.y) * sc,
                          __half2float(bv.z) * sc, __half2float(bv.w) * sc};
            bf16x8 hi, lo;
            #pragma unroll
            for (int j = 0; j < 8; ++j) {
                unsigned short h = f2bf(v[j]);
                hi[j] = (short)h;
                lo[j] = (short)f2bf(v[j] - bf2f(h));
            }
            Ah[rt][q] = hi; Al[rt][q] = lo;
        }
    }

    f32x4 acc[2][3];
    #pragma unroll
    for (int rt = 0; rt < 2; ++rt)
        #pragma unroll
        for (int t = 0; t < 3; ++t)
            acc[rt][t] = (f32x4){0.f, 0.f, 0.f, 0.f};

    #pragma unroll
    for (int t = 0; t < 3; ++t) {
        #pragma unroll
        for (int q = 0; q < 4; ++q) {
            const int off = ((t * 4 + q) * 64 + lane) * 8;
            bf16x8 Bh = *(const bf16x8*)(Wh + off);
            bf16x8 Bl = *(const bf16x8*)(Wl + off);
            #pragma unroll
            for (int rt = 0; rt < 2; ++rt) {
                acc[rt][t] = __builtin_amdgcn_mfma_f32_16x16x32_bf16(Ah[rt][q], Bh, acc[rt][t], 0, 0, 0);
                acc[rt][t] = __builtin_amdgcn_mfma_f32_16x16x32_bf16(Ah[rt][q], Bl, acc[rt][t], 0, 0, 0);
                acc[rt][t] = __builtin_amdgcn_mfma_f32_16x16x32_bf16(Al[rt][q], Bh, acc[rt][t], 0, 0, 0);
            }
        }
    }

    #pragma unroll
    for (int rt = 0; rt < 2; ++rt) {
        int r0 = rowBase + rt * 16 + quad * 4;
        #pragma unroll
        for (int reg = 0; reg < 4; ++reg) {
            int r = r0 + reg;
            if (r >= n) continue;
            __half* gr = G + (size_t)r * 64;    // padded stride
            #pragma unroll
            for (int t = 0; t < 3; ++t) {
                int col = t * 16 + m;
                if (col < 40) gr[col] = __float2half(acc[rt][t][reg]);
            }
        }
    }
}

// 128-dim gather (fp16 in, fp16 out): h1[node] = relu((sum H[src]) * ni + b)
// 16 lanes per node, one half8 (16 B) per lane; 16 nodes per 256-thread block.
__global__ __launch_bounds__(256) void gather_kernel(
        const __half* __restrict__ H, const int* __restrict__ row_ptr,
        const int* __restrict__ deg, const int* __restrict__ csr_src,
        const float* __restrict__ norm_in, const float* __restrict__ b,
        __half* __restrict__ out, int n) {
    const int tid  = threadIdx.x;
    const int node = blockIdx.x * 16 + (tid >> 4);
    const int c    = (tid & 15) * 8;
    if (node >= n) return;

    const int start = row_ptr[node];
    const int cnt   = deg[node];
    float acc[8] = {0.f, 0.f, 0.f, 0.f, 0.f, 0.f, 0.f, 0.f};

    int j = 0;
    for (; j + 4 <= cnt; j += 4) {
        int s0 = csr_src[start + j];
        int s1 = csr_src[start + j + 1];
        int s2 = csr_src[start + j + 2];
        int s3 = csr_src[start + j + 3];
        half8 v0 = *(const half8*)(H + (long long)s0 * 128 + c);
        half8 v1 = *(const half8*)(H + (long long)s1 * 128 + c);
        half8 v2 = *(const half8*)(H + (long long)s2 * 128 + c);
        half8 v3 = *(const half8*)(H + (long long)s3 * 128 + c);
        #pragma unroll
        for (int k = 0; k < 8; ++k)
            acc[k] += (__half2float(v0.h[k]) + __half2float(v1.h[k]))
                    + (__half2float(v2.h[k]) + __half2float(v3.h[k]));
    }
    for (; j < cnt; ++j) {
        int s0 = csr_src[start + j];
        half8 v0 = *(const half8*)(H + (long long)s0 * 128 + c);
        #pragma unroll
        for (int k = 0; k < 8; ++k) acc[k] += __half2float(v0.h[k]);
    }

    float ni = norm_in[node];
    float4 b0 = *(const float4*)(b + c);
    float4 b1v = *(const float4*)(b + c + 4);
    half8 o;
    o.h[0] = __float2half(fmaxf(acc[0] * ni + b0.x, 0.f));
    o.h[1] = __float2half(fmaxf(acc[1] * ni + b0.y, 0.f));
    o.h[2] = __float2half(fmaxf(acc[2] * ni + b0.z, 0.f));
    o.h[3] = __float2half(fmaxf(acc[3] * ni + b0.w, 0.f));
    o.h[4] = __float2half(fmaxf(acc[4] * ni + b1v.x, 0.f));
    o.h[5] = __float2half(fmaxf(acc[5] * ni + b1v.y, 0.f));
    o.h[6] = __float2half(fmaxf(acc[6] * ni + b1v.z, 0.f));
    o.h[7] = __float2half(fmaxf(acc[7] * ni + b1v.w, 0.f));
    *(half8*)(out + (long long)node * 128 + c) = o;
}

// 40-dim gather (fp16 in, PADDED stride 64; fp32 out): out = (sum G[src])*ni + b2p
// 5 lanes per node, one half8 (16 B) each.
__global__ __launch_bounds__(256) void gather40_kernel(
        const __half* __restrict__ G, const int* __restrict__ row_ptr,
        const int* __restrict__ deg, const int* __restrict__ csr_src,
        const float* __restrict__ norm_in, const float* __restrict__ b2p,
        float* __restrict__ out, int n) {
    const int t = blockIdx.x * 256 + threadIdx.x;
    if (t >= n * 5) return;
    const int node = t / 5;
    const int c    = (t - node * 5) * 8;

    const int start = row_ptr[node];
    const int cnt   = deg[node];
    float acc[8] = {0.f, 0.f, 0.f, 0.f, 0.f, 0.f, 0.f, 0.f};

    int j = 0;
    for (; j + 4 <= cnt; j += 4) {
        int s0 = csr_src[start + j];
        int s1 = csr_src[start + j + 1];
        int s2 = csr_src[start + j + 2];
        int s3 = csr_src[start + j + 3];
        half8 v0 = *(const half8*)(G + (long long)s0 * 64 + c);
        half8 v1 = *(const half8*)(G + (long long)s1 * 64 + c);
        half8 v2 = *(const half8*)(G + (long long)s2 * 64 + c);
        half8 v3 = *(const half8*)(G + (long long)s3 * 64 + c);
        #pragma unroll
        for (int k = 0; k < 8; ++k)
            acc[k] += (__half2float(v0.h[k]) + __half2float(v1.h[k]))
                    + (__half2float(v2.h[k]) + __half2float(v3.h[k]));
    }
    for (; j < cnt; ++j) {
        int s0 = csr_src[start + j];
        half8 v0 = *(const half8*)(G + (long long)s0 * 64 + c);
        #pragma unroll
        for (int k = 0; k < 8; ++k) acc[k] += __half2float(v0.h[k]);
    }

    float ni = norm_in[node];
    float4 o0, o1;
    o0.x = acc[0] * ni + b2p[c + 0];
    o0.y = acc[1] * ni + b2p[c + 1];
    o0.z = acc[2] * ni + b2p[c + 2];
    o0.w = acc[3] * ni + b2p[c + 3];
    o1.x = acc[4] * ni + b2p[c + 4];
    o1.y = acc[5] * ni + b2p[c + 5];
    o1.z = acc[6] * ni + b2p[c + 6];
    o1.w = acc[7] * ni + b2p[c + 7];
    float* op = out + (long long)node * 40 + c;
    *(float4*)(op)     = o0;
    *(float4*)(op + 4) = o1;
}

extern "C" void kernel_launch(void* const* d_in, const int* in_sizes, int n_in,
                              void* d_out, int out_size, void* d_ws, size_t ws_size,
                              hipStream_t stream) {
    const float* x   = (const float*)d_in[0];
    const int*   ei  = (const int*)  d_in[1];
    const float* W1  = (const float*)d_in[2];
    const float* b1  = (const float*)d_in[3];
    const float* W2  = (const float*)d_in[4];
    const float* b2  = (const float*)d_in[5];
    const float* Wfc = (const float*)d_in[6];
    const float* bfc = (const float*)d_in[7];
    float* out = (float*)d_out;

    const int N = in_sizes[0] / 128;
    const int E = in_sizes[1] / 2;
    const int* src = ei;
    const int* dst = ei + E;

    const int nbuck = (N + 511) >> 9;                  // 196
    const int B1 = (E + CHUNK - 1) / CHUNK;            // 391 partition blocks

    char* p = (char*)d_ws;
    float* norm_out = (float*)p; p += (size_t)N * 4;
    float* norm_in  = (float*)p; p += (size_t)N * 4;
    float* bufA     = (float*)p; p += (size_t)N * 128 * 4;   // h1pre fp16, then G fp16
    float* bufB     = (float*)p; p += (size_t)N * 128 * 4;   // h1 fp16 (early: slabs)
    int*   deg_in   = (int*)p;   p += (size_t)N * 4;
    int*   row_ptr  = (int*)p;   p += (size_t)N * 4;
    int*   csr_src  = (int*)p;   p += (size_t)nbuck * SLAB * 4;   // slab-indexed CSR
    int*   cur_d    = (int*)p;   p += (size_t)1024 * 4;
    int*   cur_s    = (int*)p;   p += (size_t)1024 * 4;
    float* b2p      = (float*)p; p += (size_t)64 * 4;
    unsigned short* Wh1 = (unsigned short*)p; p += (size_t)16384 * 2;
    unsigned short* Wl1 = (unsigned short*)p; p += (size_t)16384 * 2;
    unsigned short* Wh2 = (unsigned short*)p; p += (size_t)6144 * 2;
    unsigned short* Wl2 = (unsigned short*)p; p += (size_t)6144 * 2;

    // partition slabs alias bufB (consumed before gather writes h1 there)
    unsigned int*   ppack  = (unsigned int*)bufB;
    unsigned short* es_loc = (unsigned short*)(ppack + (size_t)nbuck * SLAB);

    __half* h1pre = (__half*)bufA;   // N x 128 fp16
    __half* G     = (__half*)bufA;   // N x 64 fp16 PADDED (reused after gather1)
    __half* h1    = (__half*)bufB;   // N x 128 fp16

    const int T = 256;

    // setup: cursors + W1/W2p frag conversion + b2p (22568 threads)
    setup_kernel<<<(16384 + 6144 + 40 + T - 1) / T, T, 0, stream>>>(
        W1, W2, Wfc, b2, bfc, Wh1, Wl1, Wh2, Wl2, b2p, cur_d, cur_s, nbuck);
    // partition + norms (merged fine pass)
    scatter_res_kernel<<<B1, T, 0, stream>>>(src, dst, cur_d, cur_s, ppack, es_loc, E);
    fine_kernel<<<nbuck, T, 0, stream>>>(ppack, cur_d, es_loc, cur_s,
                                         deg_in, norm_in, row_ptr, csr_src,
                                         norm_out, N);

    // layer 0: h1 = relu(gather(Xn @ W1) * ni + b1)   [MFMA bf16-split GEMM]
    const int gemm_grid = (N + 127) / 128;
    gemm128<<<gemm_grid, T, 0, stream>>>(x, norm_out, Wh1, Wl1, h1pre, N);
    const int gather_grid = (N + 15) / 16;
    gather_kernel<<<gather_grid, T, 0, stream>>>(h1pre, row_ptr, deg_in, csr_src,
                                                 norm_in, b1, h1, N);
    // layer 1 + FC fused: out = gather((h1*no) @ W2p) * ni + b2p  [MFMA]
    gemm40<<<gemm_grid, T, 0, stream>>>(h1, norm_out, Wh2, Wl2, G, N);
    gather40_kernel<<<((size_t)N * 5 + T - 1) / T, T, 0, stream>>>(
        G, row_ptr, deg_in, csr_src, norm_in, b2p, out, N);
}

// Round 5
// 289.962 us; speedup vs baseline: 1.9139x; 1.0273x over previous
//
#include <hip/hip_runtime.h>
#include <hip/hip_fp16.h>

// ---------------------------------------------------------------------------
// GCN: 2x GraphConv (norm='both') + FC.  fp32 math, fp16 intermediates.
// R2..R8: 5943 -> 325 us (CSR gather, fold FC, MFMA GEMMs, fp16, no atomics).
// R9: reservation partition (323 us).
// R10: gather+gemm fusion REGRESSED (394 us): occupancy 68%->16%. Reverted.
// R11: gather1 16 lanes x half8; CHUNK 4096. 323 us.
// R12/R13: XCD-affinity sliced gather. Both REGRESSED (351/555 us): per-XCD
//      L2 replication of shared tables is structural. Theory abandoned.
// R14: revert + pad G rows 80B->128B + merged fine pass. 314.7 us.
// R15: W-frag preconversion in setup; GEMMs LDS-free, B-frags from L2-hot
//      global. 297.9 us. gemm128 steady-state now below gather floor.
// R16: partition phase is the hidden ~50 us: fine ran 196 blocks (0.77/CU,
//      3/4 of GPU idle). Buckets 512->128 nodes: fine = 782 blocks (3/CU),
//      per-block stream 8163->2046 entries; scatter_res gets 782 bins (less
//      LDS-atomic contention); es_loc -> uchar. SLAB 3072 = mean+22sigma.
// ---------------------------------------------------------------------------

#define CHUNK    4096   // edges per partition block (391 blocks)
#define NBK      800    // bin array size (>= nbuck=782)
#define SLAB     3072   // per-bucket slab capacity (mean 2046 + ~22 sigma)

typedef __attribute__((ext_vector_type(8))) short bf16x8;
typedef __attribute__((ext_vector_type(4))) float f32x4;

struct __align__(8)  half4 { __half x, y, z, w; };
struct __align__(16) half8 { __half h[8]; };

__device__ __forceinline__ unsigned short f2bf(float f) {
    union { float f; unsigned u; } v; v.f = f;
    unsigned r = v.u + 0x7FFFu + ((v.u >> 16) & 1u);   // RNE
    return (unsigned short)(r >> 16);
}
__device__ __forceinline__ float bf2f(unsigned short h) {
    union { unsigned u; float f; } v; v.u = ((unsigned)h) << 16;
    return v.f;
}

// ---------------------------------------------------------------------------
// setup: cursors, W1 -> frag-ordered bf16-split (Wh1/Wl1, 16384 each),
// W2p = W2@Wfc folded+converted (Wh2/Wl2, 48x128 = 6144 each, cols>=40 zero),
// b2p = b2@Wfc + bfc.
// ---------------------------------------------------------------------------
__global__ void setup_kernel(const float* __restrict__ W1, const float* __restrict__ W2,
                             const float* __restrict__ Wfc,
                             const float* __restrict__ b2, const float* __restrict__ bfc,
                             unsigned short* __restrict__ Wh1, unsigned short* __restrict__ Wl1,
                             unsigned short* __restrict__ Wh2, unsigned short* __restrict__ Wl2,
                             float* __restrict__ b2p,
                             int* __restrict__ cur_d, int* __restrict__ cur_s, int nbuck) {
    int idx = blockIdx.x * blockDim.x + threadIdx.x;
    if (idx < nbuck) { cur_d[idx] = idx * SLAB; cur_s[idx] = idx * SLAB; }

    if (idx < 16384) {
        // W1[k][nn] -> frag pos for gemm128
        int k = idx >> 7, nn = idx & 127;
        float v = W1[idx];
        int q = k >> 5, j = k & 7, lb = ((k >> 3) & 3) * 16;
        int tcol = nn >> 4;
        int l = lb + (nn & 15);
        int pos = ((tcol * 4 + q) * 64 + l) * 8 + j;
        unsigned short h = f2bf(v);
        Wh1[pos] = h;
        Wl1[pos] = f2bf(v - bf2f(h));
    } else if (idx < 16384 + 6144) {
        // W2p[k][nn] = dot(W2 row k, Wfc col nn) -> frag pos for gemm40
        int i2 = idx - 16384;
        int k = i2 / 48, nn = i2 - k * 48;
        float v = 0.f;
        if (nn < 40) {
            const float* w2row = W2 + k * 128;
            #pragma unroll 8
            for (int jj = 0; jj < 128; ++jj) v += w2row[jj] * Wfc[jj * 40 + nn];
        }
        int t = nn >> 4, q = k >> 5, j = k & 7;
        int l = ((k >> 3) & 3) * 16 + (nn & 15);
        int pos = ((t * 4 + q) * 64 + l) * 8 + j;
        unsigned short h = f2bf(v);
        Wh2[pos] = h;
        Wl2[pos] = f2bf(v - bf2f(h));
    } else if (idx < 16384 + 6144 + 40) {
        int c = idx - (16384 + 6144);
        float a = bfc[c];
        #pragma unroll 8
        for (int j = 0; j < 128; ++j) a += b2[j] * Wfc[j * 40 + c];
        b2p[c] = a;
    }
}

// ------------- single-pass partition with per-bucket slab reservation -------
// buckets = node>>7 (128 nodes each, 782 buckets), 782 LDS bins.
__global__ __launch_bounds__(256) void scatter_res_kernel(
        const int* __restrict__ src, const int* __restrict__ dst,
        int* __restrict__ cur_d, int* __restrict__ cur_s,
        unsigned int* __restrict__ ppack, unsigned char* __restrict__ es_loc,
        int E) {
    __shared__ int hd[NBK], hs[NBK], bd[NBK], bs[NBK];
    const int tid = threadIdx.x;
    for (int i = tid; i < NBK; i += 256) { hd[i] = 0; hs[i] = 0; }
    __syncthreads();
    const int base = blockIdx.x * CHUNK;
    const int end  = min(base + CHUNK, E);
    for (int e = base + tid; e < end; e += 256) {
        atomicAdd(&hd[((unsigned)dst[e]) >> 7], 1);
        atomicAdd(&hs[((unsigned)src[e]) >> 7], 1);
    }
    __syncthreads();
    for (int i = tid; i < NBK; i += 256) {
        int cd = hd[i];
        bd[i] = cd ? atomicAdd(&cur_d[i], cd) : 0;
        hd[i] = 0;
        int cs = hs[i];
        bs[i] = cs ? atomicAdd(&cur_s[i], cs) : 0;
        hs[i] = 0;
    }
    __syncthreads();
    for (int e = base + tid; e < end; e += 256) {
        int d = dst[e], s = src[e];
        unsigned bin_d = ((unsigned)d) >> 7;
        int pos = bd[bin_d] + atomicAdd(&hd[bin_d], 1);
        ppack[pos] = (((unsigned)d & 127u) << 17) | (unsigned)s;
        unsigned bin_s = ((unsigned)s) >> 7;
        int ps = bs[bin_s] + atomicAdd(&hs[bin_s], 1);
        es_loc[ps] = (unsigned char)(s & 127);
    }
}

// ------------- per-bucket fine pass: dst (CSR) + src (norm_out) merged ------
// one block per 128-node bucket (782 blocks, ~2046 entries each)
__global__ __launch_bounds__(256) void fine_kernel(
        const unsigned int* __restrict__ ppack, const int* __restrict__ cur_d,
        const unsigned char* __restrict__ es_loc, const int* __restrict__ cur_s,
        int* __restrict__ deg_in, float* __restrict__ norm_in,
        int* __restrict__ row_ptr, int* __restrict__ csr_src,
        float* __restrict__ norm_out, int N_) {
    __shared__ int h[128];
    __shared__ int psum[128];
    const int tid = threadIdx.x;
    const int b = blockIdx.x;
    const int start = b * SLAB;
    const int node  = (b << 7) + tid;

    // ---- dst: histogram -> prefix -> CSR scatter ----
    const int end_d = cur_d[b];
    if (tid < 128) h[tid] = 0;
    __syncthreads();
    for (int i = start + tid; i < end_d; i += 256)
        atomicAdd(&h[ppack[i] >> 17], 1);
    __syncthreads();

    int a = 0;
    if (tid < 128) { a = h[tid]; psum[tid] = a; }
    __syncthreads();
    for (int off = 1; off < 128; off <<= 1) {
        int t = 0;
        if (tid < 128 && tid >= off) t = psum[tid - off];
        __syncthreads();
        if (tid < 128) psum[tid] += t;
        __syncthreads();
    }

    if (tid < 128) {
        int base0 = psum[tid] - a + start;   // slab-local CSR position
        if (node < N_) {
            deg_in[node]  = a;
            row_ptr[node] = base0;
            norm_in[node] = rsqrtf((float)(a < 1 ? 1 : a));
        }
        h[tid] = base0;
    }
    __syncthreads();

    for (int i = start + tid; i < end_d; i += 256) {
        unsigned int pk = ppack[i];
        int pos = atomicAdd(&h[pk >> 17], 1);
        csr_src[pos] = (int)(pk & 0x1FFFFu);
    }
    __syncthreads();

    // ---- src: histogram -> norm_out ----
    const int end_s = cur_s[b];
    if (tid < 128) h[tid] = 0;
    __syncthreads();
    for (int i = start + tid; i < end_s; i += 256)
        atomicAdd(&h[(int)es_loc[i]], 1);
    __syncthreads();

    if (tid < 128 && node < N_) {
        int d = h[tid];
        norm_out[node] = rsqrtf((float)(d < 1 ? 1 : d));
    }
}

// ---------------------------------------------------------------------------
// Y[nrows x 128] (fp16) = (X * scale[row]) @ W1  via MFMA bf16 split.
// B-frags from preconverted global Wh/Wl (L2-hot, coalesced 16B/lane).
// No LDS, no barriers -> VGPR-bound occupancy.
// ---------------------------------------------------------------------------
__global__ __launch_bounds__(256, 3) void gemm128(
        const float* __restrict__ X, const float* __restrict__ scale,
        const unsigned short* __restrict__ Wh, const unsigned short* __restrict__ Wl,
        __half* __restrict__ Y, int nrows) {
    const int tid  = threadIdx.x;
    const int lane = tid & 63;
    const int w    = tid >> 6;
    const int m    = lane & 15;
    const int quad = lane >> 4;
    const int rowBase = blockIdx.x * 128 + w * 32;

    bf16x8 Ah[2][4], Al[2][4];
    #pragma unroll
    for (int rt = 0; rt < 2; ++rt) {
        int r = rowBase + rt * 16 + m;
        float sc = (r < nrows) ? scale[r] : 0.f;
        const float* xr = X + (size_t)(r < nrows ? r : 0) * 128;
        #pragma unroll
        for (int q = 0; q < 4; ++q) {
            int k0 = q * 32 + quad * 8;
            float4 a = *(const float4*)(xr + k0);
            float4 bv = *(const float4*)(xr + k0 + 4);
            float v[8] = {a.x * sc, a.y * sc, a.z * sc, a.w * sc,
                          bv.x * sc, bv.y * sc, bv.z * sc, bv.w * sc};
            bf16x8 hi, lo;
            #pragma unroll
            for (int j = 0; j < 8; ++j) {
                unsigned short h = f2bf(v[j]);
                hi[j] = (short)h;
                lo[j] = (short)f2bf(v[j] - bf2f(h));
            }
            Ah[rt][q] = hi; Al[rt][q] = lo;
        }
    }

    f32x4 acc[2][8];
    #pragma unroll
    for (int rt = 0; rt < 2; ++rt)
        #pragma unroll
        for (int t = 0; t < 8; ++t)
            acc[rt][t] = (f32x4){0.f, 0.f, 0.f, 0.f};

    #pragma unroll
    for (int t = 0; t < 8; ++t) {
        #pragma unroll
        for (int q = 0; q < 4; ++q) {
            const int off = ((t * 4 + q) * 64 + lane) * 8;
            bf16x8 Bh = *(const bf16x8*)(Wh + off);
            bf16x8 Bl = *(const bf16x8*)(Wl + off);
            #pragma unroll
            for (int rt = 0; rt < 2; ++rt) {
                acc[rt][t] = __builtin_amdgcn_mfma_f32_16x16x32_bf16(Ah[rt][q], Bh, acc[rt][t], 0, 0, 0);
                acc[rt][t] = __builtin_amdgcn_mfma_f32_16x16x32_bf16(Ah[rt][q], Bl, acc[rt][t], 0, 0, 0);
                acc[rt][t] = __builtin_amdgcn_mfma_f32_16x16x32_bf16(Al[rt][q], Bh, acc[rt][t], 0, 0, 0);
            }
        }
    }

    #pragma unroll
    for (int rt = 0; rt < 2; ++rt) {
        int r0 = rowBase + rt * 16 + quad * 4;
        #pragma unroll
        for (int reg = 0; reg < 4; ++reg) {
            int r = r0 + reg;
            if (r >= nrows) continue;
            __half* yr = Y + (size_t)r * 128 + m;
            #pragma unroll
            for (int t = 0; t < 8; ++t)
                yr[t * 16] = __float2half(acc[rt][t][reg]);
        }
    }
}

// ---------------------------------------------------------------------------
// G (fp16, PADDED stride 64) = (H[n x 128 fp16] * scale[row]) @ W2p.
// B-frags from preconverted global Wh2/Wl2 (48x128, cols>=40 zero).
// ---------------------------------------------------------------------------
__global__ __launch_bounds__(256, 4) void gemm40(
        const __half* __restrict__ H, const float* __restrict__ scale,
        const unsigned short* __restrict__ Wh, const unsigned short* __restrict__ Wl,
        __half* __restrict__ G, int n) {
    const int tid  = threadIdx.x;
    const int lane = tid & 63;
    const int w    = tid >> 6;
    const int m    = lane & 15;
    const int quad = lane >> 4;
    const int rowBase = blockIdx.x * 128 + w * 32;

    bf16x8 Ah[2][4], Al[2][4];
    #pragma unroll
    for (int rt = 0; rt < 2; ++rt) {
        int r = rowBase + rt * 16 + m;
        float sc = (r < n) ? scale[r] : 0.f;
        const __half* xr = H + (size_t)(r < n ? r : 0) * 128;
        #pragma unroll
        for (int q = 0; q < 4; ++q) {
            int k0 = q * 32 + quad * 8;
            half4 a = *(const half4*)(xr + k0);
            half4 bv = *(const half4*)(xr + k0 + 4);
            float v[8] = {__half2float(a.x) * sc, __half2float(a.y) * sc,
                          __half2float(a.z) * sc, __half2float(a.w) * sc,
                          __half2float(bv.x) * sc, __half2float(bv.y) * sc,
                          __half2float(bv.z) * sc, __half2float(bv.w) * sc};
            bf16x8 hi, lo;
            #pragma unroll
            for (int j = 0; j < 8; ++j) {
                unsigned short h = f2bf(v[j]);
                hi[j] = (short)h;
                lo[j] = (short)f2bf(v[j] - bf2f(h));
            }
            Ah[rt][q] = hi; Al[rt][q] = lo;
        }
    }

    f32x4 acc[2][3];
    #pragma unroll
    for (int rt = 0; rt < 2; ++rt)
        #pragma unroll
        for (int t = 0; t < 3; ++t)
            acc[rt][t] = (f32x4){0.f, 0.f, 0.f, 0.f};

    #pragma unroll
    for (int t = 0; t < 3; ++t) {
        #pragma unroll
        for (int q = 0; q < 4; ++q) {
            const int off = ((t * 4 + q) * 64 + lane) * 8;
            bf16x8 Bh = *(const bf16x8*)(Wh + off);
            bf16x8 Bl = *(const bf16x8*)(Wl + off);
            #pragma unroll
            for (int rt = 0; rt < 2; ++rt) {
                acc[rt][t] = __builtin_amdgcn_mfma_f32_16x16x32_bf16(Ah[rt][q], Bh, acc[rt][t], 0, 0, 0);
                acc[rt][t] = __builtin_amdgcn_mfma_f32_16x16x32_bf16(Ah[rt][q], Bl, acc[rt][t], 0, 0, 0);
                acc[rt][t] = __builtin_amdgcn_mfma_f32_16x16x32_bf16(Al[rt][q], Bh, acc[rt][t], 0, 0, 0);
            }
        }
    }

    #pragma unroll
    for (int rt = 0; rt < 2; ++rt) {
        int r0 = rowBase + rt * 16 + quad * 4;
        #pragma unroll
        for (int reg = 0; reg < 4; ++reg) {
            int r = r0 + reg;
            if (r >= n) continue;
            __half* gr = G + (size_t)r * 64;    // padded stride
            #pragma unroll
            for (int t = 0; t < 3; ++t) {
                int col = t * 16 + m;
                if (col < 40) gr[col] = __float2half(acc[rt][t][reg]);
            }
        }
    }
}

// 128-dim gather (fp16 in, fp16 out): h1[node] = relu((sum H[src]) * ni + b)
// 16 lanes per node, one half8 (16 B) per lane; 16 nodes per 256-thread block.
__global__ __launch_bounds__(256) void gather_kernel(
        const __half* __restrict__ H, const int* __restrict__ row_ptr,
        const int* __restrict__ deg, const int* __restrict__ csr_src,
        const float* __restrict__ norm_in, const float* __restrict__ b,
        __half* __restrict__ out, int n) {
    const int tid  = threadIdx.x;
    const int node = blockIdx.x * 16 + (tid >> 4);
    const int c    = (tid & 15) * 8;
    if (node >= n) return;

    const int start = row_ptr[node];
    const int cnt   = deg[node];
    float acc[8] = {0.f, 0.f, 0.f, 0.f, 0.f, 0.f, 0.f, 0.f};

    int j = 0;
    for (; j + 4 <= cnt; j += 4) {
        int s0 = csr_src[start + j];
        int s1 = csr_src[start + j + 1];
        int s2 = csr_src[start + j + 2];
        int s3 = csr_src[start + j + 3];
        half8 v0 = *(const half8*)(H + (long long)s0 * 128 + c);
        half8 v1 = *(const half8*)(H + (long long)s1 * 128 + c);
        half8 v2 = *(const half8*)(H + (long long)s2 * 128 + c);
        half8 v3 = *(const half8*)(H + (long long)s3 * 128 + c);
        #pragma unroll
        for (int k = 0; k < 8; ++k)
            acc[k] += (__half2float(v0.h[k]) + __half2float(v1.h[k]))
                    + (__half2float(v2.h[k]) + __half2float(v3.h[k]));
    }
    for (; j < cnt; ++j) {
        int s0 = csr_src[start + j];
        half8 v0 = *(const half8*)(H + (long long)s0 * 128 + c);
        #pragma unroll
        for (int k = 0; k < 8; ++k) acc[k] += __half2float(v0.h[k]);
    }

    float ni = norm_in[node];
    float4 b0 = *(const float4*)(b + c);
    float4 b1v = *(const float4*)(b + c + 4);
    half8 o;
    o.h[0] = __float2half(fmaxf(acc[0] * ni + b0.x, 0.f));
    o.h[1] = __float2half(fmaxf(acc[1] * ni + b0.y, 0.f));
    o.h[2] = __float2half(fmaxf(acc[2] * ni + b0.z, 0.f));
    o.h[3] = __float2half(fmaxf(acc[3] * ni + b0.w, 0.f));
    o.h[4] = __float2half(fmaxf(acc[4] * ni + b1v.x, 0.f));
    o.h[5] = __float2half(fmaxf(acc[5] * ni + b1v.y, 0.f));
    o.h[6] = __float2half(fmaxf(acc[6] * ni + b1v.z, 0.f));
    o.h[7] = __float2half(fmaxf(acc[7] * ni + b1v.w, 0.f));
    *(half8*)(out + (long long)node * 128 + c) = o;
}

// 40-dim gather (fp16 in, PADDED stride 64; fp32 out): out = (sum G[src])*ni + b2p
// 5 lanes per node, one half8 (16 B) each.
__global__ __launch_bounds__(256) void gather40_kernel(
        const __half* __restrict__ G, const int* __restrict__ row_ptr,
        const int* __restrict__ deg, const int* __restrict__ csr_src,
        const float* __restrict__ norm_in, const float* __restrict__ b2p,
        float* __restrict__ out, int n) {
    const int t = blockIdx.x * 256 + threadIdx.x;
    if (t >= n * 5) return;
    const int node = t / 5;
    const int c    = (t - node * 5) * 8;

    const int start = row_ptr[node];
    const int cnt   = deg[node];
    float acc[8] = {0.f, 0.f, 0.f, 0.f, 0.f, 0.f, 0.f, 0.f};

    int j = 0;
    for (; j + 4 <= cnt; j += 4) {
        int s0 = csr_src[start + j];
        int s1 = csr_src[start + j + 1];
        int s2 = csr_src[start + j + 2];
        int s3 = csr_src[start + j + 3];
        half8 v0 = *(const half8*)(G + (long long)s0 * 64 + c);
        half8 v1 = *(const half8*)(G + (long long)s1 * 64 + c);
        half8 v2 = *(const half8*)(G + (long long)s2 * 64 + c);
        half8 v3 = *(const half8*)(G + (long long)s3 * 64 + c);
        #pragma unroll
        for (int k = 0; k < 8; ++k)
            acc[k] += (__half2float(v0.h[k]) + __half2float(v1.h[k]))
                    + (__half2float(v2.h[k]) + __half2float(v3.h[k]));
    }
    for (; j < cnt; ++j) {
        int s0 = csr_src[start + j];
        half8 v0 = *(const half8*)(G + (long long)s0 * 64 + c);
        #pragma unroll
        for (int k = 0; k < 8; ++k) acc[k] += __half2float(v0.h[k]);
    }

    float ni = norm_in[node];
    float4 o0, o1;
    o0.x = acc[0] * ni + b2p[c + 0];
    o0.y = acc[1] * ni + b2p[c + 1];
    o0.z = acc[2] * ni + b2p[c + 2];
    o0.w = acc[3] * ni + b2p[c + 3];
    o1.x = acc[4] * ni + b2p[c + 4];
    o1.y = acc[5] * ni + b2p[c + 5];
    o1.z = acc[6] * ni + b2p[c + 6];
    o1.w = acc[7] * ni + b2p[c + 7];
    float* op = out + (long long)node * 40 + c;
    *(float4*)(op)     = o0;
    *(float4*)(op + 4) = o1;
}

extern "C" void kernel_launch(void* const* d_in, const int* in_sizes, int n_in,
                              void* d_out, int out_size, void* d_ws, size_t ws_size,
                              hipStream_t stream) {
    const float* x   = (const float*)d_in[0];
    const int*   ei  = (const int*)  d_in[1];
    const float* W1  = (const float*)d_in[2];
    const float* b1  = (const float*)d_in[3];
    const float* W2  = (const float*)d_in[4];
    const float* b2  = (const float*)d_in[5];
    const float* Wfc = (const float*)d_in[6];
    const float* bfc = (const float*)d_in[7];
    float* out = (float*)d_out;

    const int N = in_sizes[0] / 128;
    const int E = in_sizes[1] / 2;
    const int* src = ei;
    const int* dst = ei + E;

    const int nbuck = (N + 127) >> 7;                  // 782
    const int B1 = (E + CHUNK - 1) / CHUNK;            // 391 partition blocks

    char* p = (char*)d_ws;
    float* norm_out = (float*)p; p += (size_t)N * 4;
    float* norm_in  = (float*)p; p += (size_t)N * 4;
    float* bufA     = (float*)p; p += (size_t)N * 128 * 4;   // h1pre fp16, then G fp16
    float* bufB     = (float*)p; p += (size_t)N * 128 * 4;   // h1 fp16 (early: slabs)
    int*   deg_in   = (int*)p;   p += (size_t)N * 4;
    int*   row_ptr  = (int*)p;   p += (size_t)N * 4;
    int*   csr_src  = (int*)p;   p += (size_t)NBK * SLAB * 4;   // slab-indexed CSR
    int*   cur_d    = (int*)p;   p += (size_t)1024 * 4;
    int*   cur_s    = (int*)p;   p += (size_t)1024 * 4;
    float* b2p      = (float*)p; p += (size_t)64 * 4;
    unsigned short* Wh1 = (unsigned short*)p; p += (size_t)16384 * 2;
    unsigned short* Wl1 = (unsigned short*)p; p += (size_t)16384 * 2;
    unsigned short* Wh2 = (unsigned short*)p; p += (size_t)6144 * 2;
    unsigned short* Wl2 = (unsigned short*)p; p += (size_t)6144 * 2;

    // partition slabs alias bufB (consumed before gather writes h1 there)
    unsigned int*  ppack  = (unsigned int*)bufB;
    unsigned char* es_loc = (unsigned char*)(ppack + (size_t)NBK * SLAB);

    __half* h1pre = (__half*)bufA;   // N x 128 fp16
    __half* G     = (__half*)bufA;   // N x 64 fp16 PADDED (reused after gather1)
    __half* h1    = (__half*)bufB;   // N x 128 fp16

    const int T = 256;

    // setup: cursors + W1/W2p frag conversion + b2p (22568 threads)
    setup_kernel<<<(16384 + 6144 + 40 + T - 1) / T, T, 0, stream>>>(
        W1, W2, Wfc, b2, bfc, Wh1, Wl1, Wh2, Wl2, b2p, cur_d, cur_s, nbuck);
    // partition + norms (128-node buckets: 782 fine blocks)
    scatter_res_kernel<<<B1, T, 0, stream>>>(src, dst, cur_d, cur_s, ppack, es_loc, E);
    fine_kernel<<<nbuck, T, 0, stream>>>(ppack, cur_d, es_loc, cur_s,
                                         deg_in, norm_in, row_ptr, csr_src,
                                         norm_out, N);

    // layer 0: h1 = relu(gather(Xn @ W1) * ni + b1)   [MFMA bf16-split GEMM]
    const int gemm_grid = (N + 127) / 128;
    gemm128<<<gemm_grid, T, 0, stream>>>(x, norm_out, Wh1, Wl1, h1pre, N);
    const int gather_grid = (N + 15) / 16;
    gather_kernel<<<gather_grid, T, 0, stream>>>(h1pre, row_ptr, deg_in, csr_src,
                                                 norm_in, b1, h1, N);
    // layer 1 + FC fused: out = gather((h1*no) @ W2p) * ni + b2p  [MFMA]
    gemm40<<<gemm_grid, T, 0, stream>>>(h1, norm_out, Wh2, Wl2, G, N);
    gather40_kernel<<<((size_t)N * 5 + T - 1) / T, T, 0, stream>>>(
        G, row_ptr, deg_in, csr_src, norm_in, b2p, out, N);
}

// Round 6
// 279.126 us; speedup vs baseline: 1.9881x; 1.0388x over previous
//
#include <hip/hip_runtime.h>
#include <hip/hip_fp16.h>

// ---------------------------------------------------------------------------
// GCN: 2x GraphConv (norm='both') + FC.  fp32 math, fp16 intermediates.
// R2..R8: 5943 -> 325 us (CSR gather, fold FC, MFMA GEMMs, fp16, no atomics).
// R9: reservation partition (323 us).
// R10: gather+gemm fusion REGRESSED (394 us): occupancy 68%->16%. Reverted.
// R11: gather1 16 lanes x half8; CHUNK 4096. 323 us.
// R12/R13: XCD-affinity sliced gather. Both REGRESSED (351/555 us): per-XCD
//      L2 replication of shared tables is structural. Theory abandoned.
// R14: revert + pad G rows 80B->128B + merged fine pass. 314.7 us.
// R15: W-frag preconversion in setup; GEMMs LDS-free. 297.9 us.
// R16: 128-node partition buckets (fine: 196->782 blocks). 290.0 us.
//      Gather analysis: FETCH 178 MB == 8 XCDs x 22 MB compulsory (86% of
//      table touched per XCD); rate 3.0 TB/s == ~64 miss-lines/CU x 128B /
//      ~700ns. Compulsory + concurrency-capped -> gather read path is at its
//      structural floor. Stop attacking it; delete traffic around it.
// R17: fuse gemm40 into gather epilogue: block stages its 16 h1 rows in
//      8.4 KB LDS, waves 0-2 compute G[16x40] via MFMA from preconverted
//      Wh2/Wl2. h1 (25.6 MB write + 25.6 MB read) never materialized; one
//      launch fewer. launch_bounds(256,4) caps VGPR=128 for gather occupancy.
// ---------------------------------------------------------------------------

#define CHUNK    4096   // edges per partition block (391 blocks)
#define NBK      800    // bin array size (>= nbuck=782)
#define SLAB     3072   // per-bucket slab capacity (mean 2046 + ~22 sigma)

typedef __attribute__((ext_vector_type(8))) short bf16x8;
typedef __attribute__((ext_vector_type(4))) float f32x4;

struct __align__(8)  half4 { __half x, y, z, w; };
struct __align__(16) half8 { __half h[8]; };

__device__ __forceinline__ unsigned short f2bf(float f) {
    union { float f; unsigned u; } v; v.f = f;
    unsigned r = v.u + 0x7FFFu + ((v.u >> 16) & 1u);   // RNE
    return (unsigned short)(r >> 16);
}
__device__ __forceinline__ float bf2f(unsigned short h) {
    union { unsigned u; float f; } v; v.u = ((unsigned)h) << 16;
    return v.f;
}

// ---------------------------------------------------------------------------
// setup: cursors, W1 -> frag-ordered bf16-split (Wh1/Wl1, 16384 each),
// W2p = W2@Wfc folded+converted (Wh2/Wl2, 48x128 = 6144 each, cols>=40 zero),
// b2p = b2@Wfc + bfc.
// ---------------------------------------------------------------------------
__global__ void setup_kernel(const float* __restrict__ W1, const float* __restrict__ W2,
                             const float* __restrict__ Wfc,
                             const float* __restrict__ b2, const float* __restrict__ bfc,
                             unsigned short* __restrict__ Wh1, unsigned short* __restrict__ Wl1,
                             unsigned short* __restrict__ Wh2, unsigned short* __restrict__ Wl2,
                             float* __restrict__ b2p,
                             int* __restrict__ cur_d, int* __restrict__ cur_s, int nbuck) {
    int idx = blockIdx.x * blockDim.x + threadIdx.x;
    if (idx < nbuck) { cur_d[idx] = idx * SLAB; cur_s[idx] = idx * SLAB; }

    if (idx < 16384) {
        // W1[k][nn] -> frag pos for gemm128
        int k = idx >> 7, nn = idx & 127;
        float v = W1[idx];
        int q = k >> 5, j = k & 7, lb = ((k >> 3) & 3) * 16;
        int tcol = nn >> 4;
        int l = lb + (nn & 15);
        int pos = ((tcol * 4 + q) * 64 + l) * 8 + j;
        unsigned short h = f2bf(v);
        Wh1[pos] = h;
        Wl1[pos] = f2bf(v - bf2f(h));
    } else if (idx < 16384 + 6144) {
        // W2p[k][nn] = dot(W2 row k, Wfc col nn) -> frag pos for fused gemm40
        int i2 = idx - 16384;
        int k = i2 / 48, nn = i2 - k * 48;
        float v = 0.f;
        if (nn < 40) {
            const float* w2row = W2 + k * 128;
            #pragma unroll 8
            for (int jj = 0; jj < 128; ++jj) v += w2row[jj] * Wfc[jj * 40 + nn];
        }
        int t = nn >> 4, q = k >> 5, j = k & 7;
        int l = ((k >> 3) & 3) * 16 + (nn & 15);
        int pos = ((t * 4 + q) * 64 + l) * 8 + j;
        unsigned short h = f2bf(v);
        Wh2[pos] = h;
        Wl2[pos] = f2bf(v - bf2f(h));
    } else if (idx < 16384 + 6144 + 40) {
        int c = idx - (16384 + 6144);
        float a = bfc[c];
        #pragma unroll 8
        for (int j = 0; j < 128; ++j) a += b2[j] * Wfc[j * 40 + c];
        b2p[c] = a;
    }
}

// ------------- single-pass partition with per-bucket slab reservation -------
// buckets = node>>7 (128 nodes each, 782 buckets), 782 LDS bins.
__global__ __launch_bounds__(256) void scatter_res_kernel(
        const int* __restrict__ src, const int* __restrict__ dst,
        int* __restrict__ cur_d, int* __restrict__ cur_s,
        unsigned int* __restrict__ ppack, unsigned char* __restrict__ es_loc,
        int E) {
    __shared__ int hd[NBK], hs[NBK], bd[NBK], bs[NBK];
    const int tid = threadIdx.x;
    for (int i = tid; i < NBK; i += 256) { hd[i] = 0; hs[i] = 0; }
    __syncthreads();
    const int base = blockIdx.x * CHUNK;
    const int end  = min(base + CHUNK, E);
    for (int e = base + tid; e < end; e += 256) {
        atomicAdd(&hd[((unsigned)dst[e]) >> 7], 1);
        atomicAdd(&hs[((unsigned)src[e]) >> 7], 1);
    }
    __syncthreads();
    for (int i = tid; i < NBK; i += 256) {
        int cd = hd[i];
        bd[i] = cd ? atomicAdd(&cur_d[i], cd) : 0;
        hd[i] = 0;
        int cs = hs[i];
        bs[i] = cs ? atomicAdd(&cur_s[i], cs) : 0;
        hs[i] = 0;
    }
    __syncthreads();
    for (int e = base + tid; e < end; e += 256) {
        int d = dst[e], s = src[e];
        unsigned bin_d = ((unsigned)d) >> 7;
        int pos = bd[bin_d] + atomicAdd(&hd[bin_d], 1);
        ppack[pos] = (((unsigned)d & 127u) << 17) | (unsigned)s;
        unsigned bin_s = ((unsigned)s) >> 7;
        int ps = bs[bin_s] + atomicAdd(&hs[bin_s], 1);
        es_loc[ps] = (unsigned char)(s & 127);
    }
}

// ------------- per-bucket fine pass: dst (CSR) + src (norm_out) merged ------
// one block per 128-node bucket (782 blocks, ~2046 entries each)
__global__ __launch_bounds__(256) void fine_kernel(
        const unsigned int* __restrict__ ppack, const int* __restrict__ cur_d,
        const unsigned char* __restrict__ es_loc, const int* __restrict__ cur_s,
        int* __restrict__ deg_in, float* __restrict__ norm_in,
        int* __restrict__ row_ptr, int* __restrict__ csr_src,
        float* __restrict__ norm_out, int N_) {
    __shared__ int h[128];
    __shared__ int psum[128];
    const int tid = threadIdx.x;
    const int b = blockIdx.x;
    const int start = b * SLAB;
    const int node  = (b << 7) + tid;

    // ---- dst: histogram -> prefix -> CSR scatter ----
    const int end_d = cur_d[b];
    if (tid < 128) h[tid] = 0;
    __syncthreads();
    for (int i = start + tid; i < end_d; i += 256)
        atomicAdd(&h[ppack[i] >> 17], 1);
    __syncthreads();

    int a = 0;
    if (tid < 128) { a = h[tid]; psum[tid] = a; }
    __syncthreads();
    for (int off = 1; off < 128; off <<= 1) {
        int t = 0;
        if (tid < 128 && tid >= off) t = psum[tid - off];
        __syncthreads();
        if (tid < 128) psum[tid] += t;
        __syncthreads();
    }

    if (tid < 128) {
        int base0 = psum[tid] - a + start;   // slab-local CSR position
        if (node < N_) {
            deg_in[node]  = a;
            row_ptr[node] = base0;
            norm_in[node] = rsqrtf((float)(a < 1 ? 1 : a));
        }
        h[tid] = base0;
    }
    __syncthreads();

    for (int i = start + tid; i < end_d; i += 256) {
        unsigned int pk = ppack[i];
        int pos = atomicAdd(&h[pk >> 17], 1);
        csr_src[pos] = (int)(pk & 0x1FFFFu);
    }
    __syncthreads();

    // ---- src: histogram -> norm_out ----
    const int end_s = cur_s[b];
    if (tid < 128) h[tid] = 0;
    __syncthreads();
    for (int i = start + tid; i < end_s; i += 256)
        atomicAdd(&h[(int)es_loc[i]], 1);
    __syncthreads();

    if (tid < 128 && node < N_) {
        int d = h[tid];
        norm_out[node] = rsqrtf((float)(d < 1 ? 1 : d));
    }
}

// ---------------------------------------------------------------------------
// Y[nrows x 128] (fp16) = (X * scale[row]) @ W1  via MFMA bf16 split.
// B-frags from preconverted global Wh/Wl (L2-hot, coalesced 16B/lane).
// ---------------------------------------------------------------------------
__global__ __launch_bounds__(256, 3) void gemm128(
        const float* __restrict__ X, const float* __restrict__ scale,
        const unsigned short* __restrict__ Wh, const unsigned short* __restrict__ Wl,
        __half* __restrict__ Y, int nrows) {
    const int tid  = threadIdx.x;
    const int lane = tid & 63;
    const int w    = tid >> 6;
    const int m    = lane & 15;
    const int quad = lane >> 4;
    const int rowBase = blockIdx.x * 128 + w * 32;

    bf16x8 Ah[2][4], Al[2][4];
    #pragma unroll
    for (int rt = 0; rt < 2; ++rt) {
        int r = rowBase + rt * 16 + m;
        float sc = (r < nrows) ? scale[r] : 0.f;
        const float* xr = X + (size_t)(r < nrows ? r : 0) * 128;
        #pragma unroll
        for (int q = 0; q < 4; ++q) {
            int k0 = q * 32 + quad * 8;
            float4 a = *(const float4*)(xr + k0);
            float4 bv = *(const float4*)(xr + k0 + 4);
            float v[8] = {a.x * sc, a.y * sc, a.z * sc, a.w * sc,
                          bv.x * sc, bv.y * sc, bv.z * sc, bv.w * sc};
            bf16x8 hi, lo;
            #pragma unroll
            for (int j = 0; j < 8; ++j) {
                unsigned short h = f2bf(v[j]);
                hi[j] = (short)h;
                lo[j] = (short)f2bf(v[j] - bf2f(h));
            }
            Ah[rt][q] = hi; Al[rt][q] = lo;
        }
    }

    f32x4 acc[2][8];
    #pragma unroll
    for (int rt = 0; rt < 2; ++rt)
        #pragma unroll
        for (int t = 0; t < 8; ++t)
            acc[rt][t] = (f32x4){0.f, 0.f, 0.f, 0.f};

    #pragma unroll
    for (int t = 0; t < 8; ++t) {
        #pragma unroll
        for (int q = 0; q < 4; ++q) {
            const int off = ((t * 4 + q) * 64 + lane) * 8;
            bf16x8 Bh = *(const bf16x8*)(Wh + off);
            bf16x8 Bl = *(const bf16x8*)(Wl + off);
            #pragma unroll
            for (int rt = 0; rt < 2; ++rt) {
                acc[rt][t] = __builtin_amdgcn_mfma_f32_16x16x32_bf16(Ah[rt][q], Bh, acc[rt][t], 0, 0, 0);
                acc[rt][t] = __builtin_amdgcn_mfma_f32_16x16x32_bf16(Ah[rt][q], Bl, acc[rt][t], 0, 0, 0);
                acc[rt][t] = __builtin_amdgcn_mfma_f32_16x16x32_bf16(Al[rt][q], Bh, acc[rt][t], 0, 0, 0);
            }
        }
    }

    #pragma unroll
    for (int rt = 0; rt < 2; ++rt) {
        int r0 = rowBase + rt * 16 + quad * 4;
        #pragma unroll
        for (int reg = 0; reg < 4; ++reg) {
            int r = r0 + reg;
            if (r >= nrows) continue;
            __half* yr = Y + (size_t)r * 128 + m;
            #pragma unroll
            for (int t = 0; t < 8; ++t)
                yr[t * 16] = __float2half(acc[rt][t][reg]);
        }
    }
}

// ---------------------------------------------------------------------------
// FUSED gather + layer-1 GEMM.
// Phase 1 (all 256 threads): h1[node] = relu((sum H[src]) * ni + b1) for the
//   block's 16 nodes; 16 lanes x half8 per node -> fp32 rows staged in LDS.
// Phase 2 (waves 0-2): G[16 x 40] = (h1 * norm_out[row]) @ W2p via MFMA,
//   B-frags from preconverted Wh2/Wl2 (identical addressing to old gemm40).
// h1 never touches global memory (saves 51.2 MB round-trip + one launch).
// ---------------------------------------------------------------------------
__global__ __launch_bounds__(256, 4) void gather_kernel(
        const __half* __restrict__ H, const int* __restrict__ row_ptr,
        const int* __restrict__ deg, const int* __restrict__ csr_src,
        const float* __restrict__ norm_in, const float* __restrict__ b,
        const float* __restrict__ norm_out,
        const unsigned short* __restrict__ Wh2, const unsigned short* __restrict__ Wl2,
        __half* __restrict__ G, int n) {
    __shared__ float h1s[16][132];   // 8.4 KB; stride 132 -> 2-way bank alias max
    const int tid   = threadIdx.x;
    const int node0 = blockIdx.x * 16;
    const int g     = tid >> 4;              // node-in-block 0..15
    const int node  = node0 + g;
    const int c     = (tid & 15) * 8;        // column group
    const bool active = node < n;

    int start = 0, cnt = 0;
    if (active) { start = row_ptr[node]; cnt = deg[node]; }
    float acc[8] = {0.f, 0.f, 0.f, 0.f, 0.f, 0.f, 0.f, 0.f};

    int j = 0;
    for (; j + 4 <= cnt; j += 4) {
        int s0 = csr_src[start + j];
        int s1 = csr_src[start + j + 1];
        int s2 = csr_src[start + j + 2];
        int s3 = csr_src[start + j + 3];
        half8 v0 = *(const half8*)(H + (long long)s0 * 128 + c);
        half8 v1 = *(const half8*)(H + (long long)s1 * 128 + c);
        half8 v2 = *(const half8*)(H + (long long)s2 * 128 + c);
        half8 v3 = *(const half8*)(H + (long long)s3 * 128 + c);
        #pragma unroll
        for (int k = 0; k < 8; ++k)
            acc[k] += (__half2float(v0.h[k]) + __half2float(v1.h[k]))
                    + (__half2float(v2.h[k]) + __half2float(v3.h[k]));
    }
    for (; j < cnt; ++j) {
        int s0 = csr_src[start + j];
        half8 v0 = *(const half8*)(H + (long long)s0 * 128 + c);
        #pragma unroll
        for (int k = 0; k < 8; ++k) acc[k] += __half2float(v0.h[k]);
    }

    float ni = active ? norm_in[node] : 0.f;
    float4 b0  = *(const float4*)(b + c);
    float4 b1v = *(const float4*)(b + c + 4);
    float bb[8] = {b0.x, b0.y, b0.z, b0.w, b1v.x, b1v.y, b1v.z, b1v.w};
    #pragma unroll
    for (int k = 0; k < 8; ++k)
        h1s[g][c + k] = active ? fmaxf(acc[k] * ni + bb[k], 0.f) : 0.f;
    __syncthreads();

    // phase 2: waves 0..2 each compute one 16-col tile of G
    const int w = tid >> 6;
    if (w < 3) {
        const int lane = tid & 63;
        const int m    = lane & 15;
        const int quad = lane >> 4;
        const int r_a  = node0 + m;
        const float sc = (r_a < n) ? norm_out[r_a] : 0.f;

        bf16x8 Ah[4], Al[4];
        #pragma unroll
        for (int q = 0; q < 4; ++q) {
            int k0 = q * 32 + quad * 8;
            const float4* hp = (const float4*)&h1s[m][k0];   // 16B-aligned
            float4 va = hp[0], vb = hp[1];
            float v[8] = {va.x * sc, va.y * sc, va.z * sc, va.w * sc,
                          vb.x * sc, vb.y * sc, vb.z * sc, vb.w * sc};
            bf16x8 hi, lo;
            #pragma unroll
            for (int jj = 0; jj < 8; ++jj) {
                unsigned short h = f2bf(v[jj]);
                hi[jj] = (short)h;
                lo[jj] = (short)f2bf(v[jj] - bf2f(h));
            }
            Ah[q] = hi; Al[q] = lo;
        }

        f32x4 a3 = (f32x4){0.f, 0.f, 0.f, 0.f};
        const int t = w;
        #pragma unroll
        for (int q = 0; q < 4; ++q) {
            const int off = ((t * 4 + q) * 64 + lane) * 8;
            bf16x8 Bh = *(const bf16x8*)(Wh2 + off);
            bf16x8 Bl = *(const bf16x8*)(Wl2 + off);
            a3 = __builtin_amdgcn_mfma_f32_16x16x32_bf16(Ah[q], Bh, a3, 0, 0, 0);
            a3 = __builtin_amdgcn_mfma_f32_16x16x32_bf16(Ah[q], Bl, a3, 0, 0, 0);
            a3 = __builtin_amdgcn_mfma_f32_16x16x32_bf16(Al[q], Bh, a3, 0, 0, 0);
        }

        const int col = t * 16 + m;
        if (col < 40) {
            const int r0 = node0 + quad * 4;
            #pragma unroll
            for (int reg = 0; reg < 4; ++reg) {
                int r = r0 + reg;
                if (r < n) G[(size_t)r * 64 + col] = __float2half(a3[reg]);
            }
        }
    }
}

// 40-dim gather (fp16 in, PADDED stride 64; fp32 out): out = (sum G[src])*ni + b2p
// 5 lanes per node, one half8 (16 B) each.
__global__ __launch_bounds__(256) void gather40_kernel(
        const __half* __restrict__ G, const int* __restrict__ row_ptr,
        const int* __restrict__ deg, const int* __restrict__ csr_src,
        const float* __restrict__ norm_in, const float* __restrict__ b2p,
        float* __restrict__ out, int n) {
    const int t = blockIdx.x * 256 + threadIdx.x;
    if (t >= n * 5) return;
    const int node = t / 5;
    const int c    = (t - node * 5) * 8;

    const int start = row_ptr[node];
    const int cnt   = deg[node];
    float acc[8] = {0.f, 0.f, 0.f, 0.f, 0.f, 0.f, 0.f, 0.f};

    int j = 0;
    for (; j + 4 <= cnt; j += 4) {
        int s0 = csr_src[start + j];
        int s1 = csr_src[start + j + 1];
        int s2 = csr_src[start + j + 2];
        int s3 = csr_src[start + j + 3];
        half8 v0 = *(const half8*)(G + (long long)s0 * 64 + c);
        half8 v1 = *(const half8*)(G + (long long)s1 * 64 + c);
        half8 v2 = *(const half8*)(G + (long long)s2 * 64 + c);
        half8 v3 = *(const half8*)(G + (long long)s3 * 64 + c);
        #pragma unroll
        for (int k = 0; k < 8; ++k)
            acc[k] += (__half2float(v0.h[k]) + __half2float(v1.h[k]))
                    + (__half2float(v2.h[k]) + __half2float(v3.h[k]));
    }
    for (; j < cnt; ++j) {
        int s0 = csr_src[start + j];
        half8 v0 = *(const half8*)(G + (long long)s0 * 64 + c);
        #pragma unroll
        for (int k = 0; k < 8; ++k) acc[k] += __half2float(v0.h[k]);
    }

    float ni = norm_in[node];
    float4 o0, o1;
    o0.x = acc[0] * ni + b2p[c + 0];
    o0.y = acc[1] * ni + b2p[c + 1];
    o0.z = acc[2] * ni + b2p[c + 2];
    o0.w = acc[3] * ni + b2p[c + 3];
    o1.x = acc[4] * ni + b2p[c + 4];
    o1.y = acc[5] * ni + b2p[c + 5];
    o1.z = acc[6] * ni + b2p[c + 6];
    o1.w = acc[7] * ni + b2p[c + 7];
    float* op = out + (long long)node * 40 + c;
    *(float4*)(op)     = o0;
    *(float4*)(op + 4) = o1;
}

extern "C" void kernel_launch(void* const* d_in, const int* in_sizes, int n_in,
                              void* d_out, int out_size, void* d_ws, size_t ws_size,
                              hipStream_t stream) {
    const float* x   = (const float*)d_in[0];
    const int*   ei  = (const int*)  d_in[1];
    const float* W1  = (const float*)d_in[2];
    const float* b1  = (const float*)d_in[3];
    const float* W2  = (const float*)d_in[4];
    const float* b2  = (const float*)d_in[5];
    const float* Wfc = (const float*)d_in[6];
    const float* bfc = (const float*)d_in[7];
    float* out = (float*)d_out;

    const int N = in_sizes[0] / 128;
    const int E = in_sizes[1] / 2;
    const int* src = ei;
    const int* dst = ei + E;

    const int nbuck = (N + 127) >> 7;                  // 782
    const int B1 = (E + CHUNK - 1) / CHUNK;            // 391 partition blocks

    char* p = (char*)d_ws;
    float* norm_out = (float*)p; p += (size_t)N * 4;
    float* norm_in  = (float*)p; p += (size_t)N * 4;
    float* bufA     = (float*)p; p += (size_t)N * 128 * 4;   // h1pre fp16
    float* bufB     = (float*)p; p += (size_t)N * 128 * 4;   // slabs, then G fp16
    int*   deg_in   = (int*)p;   p += (size_t)N * 4;
    int*   row_ptr  = (int*)p;   p += (size_t)N * 4;
    int*   csr_src  = (int*)p;   p += (size_t)NBK * SLAB * 4;   // slab-indexed CSR
    int*   cur_d    = (int*)p;   p += (size_t)1024 * 4;
    int*   cur_s    = (int*)p;   p += (size_t)1024 * 4;
    float* b2p      = (float*)p; p += (size_t)64 * 4;
    unsigned short* Wh1 = (unsigned short*)p; p += (size_t)16384 * 2;
    unsigned short* Wl1 = (unsigned short*)p; p += (size_t)16384 * 2;
    unsigned short* Wh2 = (unsigned short*)p; p += (size_t)6144 * 2;
    unsigned short* Wl2 = (unsigned short*)p; p += (size_t)6144 * 2;

    // partition slabs alias bufB (consumed by fine_kernel before gather
    // writes G there)
    unsigned int*  ppack  = (unsigned int*)bufB;
    unsigned char* es_loc = (unsigned char*)(ppack + (size_t)NBK * SLAB);

    __half* h1pre = (__half*)bufA;   // N x 128 fp16
    __half* G     = (__half*)bufB;   // N x 64 fp16 PADDED (fused-gather output)

    const int T = 256;

    // setup: cursors + W1/W2p frag conversion + b2p
    setup_kernel<<<(16384 + 6144 + 40 + T - 1) / T, T, 0, stream>>>(
        W1, W2, Wfc, b2, bfc, Wh1, Wl1, Wh2, Wl2, b2p, cur_d, cur_s, nbuck);
    // partition + norms (128-node buckets: 782 fine blocks)
    scatter_res_kernel<<<B1, T, 0, stream>>>(src, dst, cur_d, cur_s, ppack, es_loc, E);
    fine_kernel<<<nbuck, T, 0, stream>>>(ppack, cur_d, es_loc, cur_s,
                                         deg_in, norm_in, row_ptr, csr_src,
                                         norm_out, N);

    // layer 0 GEMM: h1pre = (Xn) @ W1
    const int gemm_grid = (N + 127) / 128;
    gemm128<<<gemm_grid, T, 0, stream>>>(x, norm_out, Wh1, Wl1, h1pre, N);
    // fused: gather(h1pre) -> relu -> (h1*no)@W2p -> G   (h1 stays on-chip)
    const int gather_grid = (N + 15) / 16;
    gather_kernel<<<gather_grid, T, 0, stream>>>(h1pre, row_ptr, deg_in, csr_src,
                                                 norm_in, b1, norm_out,
                                                 Wh2, Wl2, G, N);
    // final gather + bias: out = gather(G) * ni + b2p
    gather40_kernel<<<((size_t)N * 5 + T - 1) / T, T, 0, stream>>>(
        G, row_ptr, deg_in, csr_src, norm_in, b2p, out, N);
}